// Round 4
// baseline (449.695 us; speedup 1.0000x reference)
//
#include <hip/hip_runtime.h>
#include <math.h>

#define N_NODES 100000
#define N_EDGES 1600000
#define IN_DIM 500
#define HID 64
#define NCLS 16
#define KP 512     // padded K for layer-1 GEMM
#define NSTEPS 16  // KP/32
#define NB_SCAN 391  // ceil(100000/256)
#define NPAD (NB_SCAN * 256)

typedef __attribute__((ext_vector_type(8))) short short8;
typedef __attribute__((ext_vector_type(4))) float f32x4;

__device__ __forceinline__ unsigned short f2bf(float f) {
    unsigned u = __builtin_bit_cast(unsigned, f);
    return (unsigned short)((u + 0x7FFFu + ((u >> 16) & 1u)) >> 16);
}
__device__ __forceinline__ float bf2f(unsigned short s) {
    unsigned u = ((unsigned)s) << 16;
    return __builtin_bit_cast(float, u);
}
__device__ __forceinline__ unsigned pack2(unsigned short a, unsigned short b) {
    return (unsigned)a | ((unsigned)b << 16);
}

// ---------------------------------------------------------------------------
// K0: build Bt[192][512] bf16 = transpose of {w1[0], w1[1], root1}, zero-pad K.
// ---------------------------------------------------------------------------
__global__ __launch_bounds__(256) void k0_bt(
    const float* __restrict__ w1, const float* __restrict__ root1,
    unsigned short* __restrict__ Bt)
{
    const int b = blockIdx.x;  // 0..191
    const float* src;
    int c;
    if (b < 64)        { src = w1;                c = b; }
    else if (b < 128)  { src = w1 + IN_DIM * HID; c = b - 64; }
    else               { src = root1;             c = b - 128; }
    for (int k = threadIdx.x; k < KP; k += 256) {
        float v = (k < IN_DIM) ? src[k * HID + c] : 0.f;
        Bt[b * KP + k] = f2bf(v);
    }
}

// ---------------------------------------------------------------------------
// CSR build: zero, histogram, scan x3, scatter
// ---------------------------------------------------------------------------
__global__ __launch_bounds__(256) void csr_zero(int* __restrict__ cnt)
{
    const int i = blockIdx.x * 256 + threadIdx.x;
    if (i < NPAD) cnt[i] = 0;
}

__global__ __launch_bounds__(256) void csr_hist(
    const int* __restrict__ ei, int* __restrict__ cnt)
{
    for (int e = blockIdx.x * 256 + threadIdx.x; e < N_EDGES; e += gridDim.x * 256)
        atomicAdd(&cnt[ei[N_EDGES + e]], 1);
}

__global__ __launch_bounds__(256) void csr_scan1(
    const int* __restrict__ cnt, int* __restrict__ off, int* __restrict__ bsum)
{
    __shared__ int s[256];
    const int t = threadIdx.x;
    const int i = blockIdx.x * 256 + t;
    const int val = cnt[i];
    s[t] = val;
    for (int d = 1; d < 256; d <<= 1) {
        __syncthreads();
        int add = (t >= d) ? s[t - d] : 0;
        __syncthreads();
        s[t] += add;
    }
    __syncthreads();
    off[i] = s[t] - val;
    if (t == 255) bsum[blockIdx.x] = s[255];
}

__global__ __launch_bounds__(512) void csr_scan2(
    const int* __restrict__ bsum, int* __restrict__ bsumoff)
{
    __shared__ int s[512];
    const int t = threadIdx.x;
    const int val = (t < NB_SCAN) ? bsum[t] : 0;
    s[t] = val;
    for (int d = 1; d < 512; d <<= 1) {
        __syncthreads();
        int add = (t >= d) ? s[t - d] : 0;
        __syncthreads();
        s[t] += add;
    }
    __syncthreads();
    if (t < NB_SCAN) bsumoff[t] = s[t] - val;
}

__global__ __launch_bounds__(256) void csr_scan3(
    int* __restrict__ off, const int* __restrict__ bsumoff, int* __restrict__ cursor)
{
    const int i = blockIdx.x * 256 + threadIdx.x;
    const int o = off[i] + bsumoff[blockIdx.x];
    off[i] = o;
    cursor[i] = o;
}

__global__ __launch_bounds__(256) void csr_scatter(
    const int* __restrict__ ei, const float* __restrict__ ea,
    int* __restrict__ cursor, uint2* __restrict__ epk)
{
    for (int e = blockIdx.x * 256 + threadIdx.x; e < N_EDGES; e += gridDim.x * 256) {
        const int src = ei[e];
        const int dst = ei[N_EDGES + e];
        const float v = fminf(fmaxf(ea[e], 0.f), 1.f - 1e-6f);
        const int pos = atomicAdd(&cursor[dst], 1);
        epk[pos] = make_uint2((unsigned)src, __builtin_bit_cast(unsigned, v));
    }
}

// ---------------------------------------------------------------------------
// K1: bf16 MFMA GEMM, software-pipelined. C[128 x 192] per block.
// Double-buffered LDS; step s+1 global loads issued before step s MFMA,
// converted+written after (compiler places vmcnt wait before ds_write).
// One barrier per K-step.
// ---------------------------------------------------------------------------
union K1Smem {
    struct { unsigned short A[2][128 * 40]; unsigned short B[2][192 * 40]; } ab;
    unsigned short O[64 * 264];  // epilogue staging (33.8 KB < 50 KB)
};

__global__ __launch_bounds__(256) void k1_mfma(
    const float* __restrict__ x, const unsigned short* __restrict__ Bt,
    unsigned short* __restrict__ xw01, float* __restrict__ aggH)
{
    __shared__ K1Smem sm;

    const int tid = threadIdx.x;
    const int row0 = blockIdx.x * 128;
    const int w = tid >> 6;
    const int l = tid & 63;
    const int l16 = l & 15;
    const int koct = l >> 4;

    f32x4 acc[2][12];
#pragma unroll
    for (int i = 0; i < 2; ++i)
#pragma unroll
        for (int j = 0; j < 12; ++j) acc[i][j] = (f32x4){0.f, 0.f, 0.f, 0.f};

    const int arow = tid >> 1;   // 0..127
    const int ahalf = tid & 1;   // which 16-k half
    const bool rv = (row0 + arow) < N_NODES;
    const float* xrow = x + (size_t)(row0 + arow) * IN_DIM + ahalf * 16;

    float4 pa[4];
    uint4 pb[3];

    // prefetch registers -> issue global loads for step s
    auto LOAD = [&](int s) {
        const int k0 = s * 32;
#pragma unroll
        for (int j = 0; j < 4; ++j) {
            const int k = k0 + ahalf * 16 + j * 4;
            pa[j] = (rv && k < IN_DIM) ? *(const float4*)(xrow + k0 + j * 4)
                                       : make_float4(0.f, 0.f, 0.f, 0.f);
        }
#pragma unroll
        for (int i = 0; i < 3; ++i) {
            const int id = tid + i * 256;
            const int col = id >> 2, c = id & 3;
            pb[i] = *(const uint4*)&Bt[col * KP + k0 + c * 8];
        }
    };
    // convert + write prefetched regs into LDS buffer `buf`
    auto STORE = [&](int buf) {
        unsigned short t16[16];
#pragma unroll
        for (int j = 0; j < 4; ++j) {
            t16[j * 4 + 0] = f2bf(pa[j].x);
            t16[j * 4 + 1] = f2bf(pa[j].y);
            t16[j * 4 + 2] = f2bf(pa[j].z);
            t16[j * 4 + 3] = f2bf(pa[j].w);
        }
        uint4 w0, w1v;
        w0.x = pack2(t16[0], t16[1]);   w0.y = pack2(t16[2], t16[3]);
        w0.z = pack2(t16[4], t16[5]);   w0.w = pack2(t16[6], t16[7]);
        w1v.x = pack2(t16[8], t16[9]);  w1v.y = pack2(t16[10], t16[11]);
        w1v.z = pack2(t16[12], t16[13]); w1v.w = pack2(t16[14], t16[15]);
        *(uint4*)&sm.ab.A[buf][arow * 40 + ahalf * 16] = w0;
        *(uint4*)&sm.ab.A[buf][arow * 40 + ahalf * 16 + 8] = w1v;
#pragma unroll
        for (int i = 0; i < 3; ++i) {
            const int id = tid + i * 256;
            const int col = id >> 2, c = id & 3;
            *(uint4*)&sm.ab.B[buf][col * 40 + c * 8] = pb[i];
        }
    };

    LOAD(0);
    STORE(0);
    __syncthreads();

    for (int s = 0; s < NSTEPS; ++s) {
        const int cur = s & 1;
        if (s + 1 < NSTEPS) LOAD(s + 1);  // in flight during MFMA

        short8 af[2];
#pragma unroll
        for (int rb = 0; rb < 2; ++rb)
            af[rb] = *(const short8*)&sm.ab.A[cur][(w * 32 + rb * 16 + l16) * 40 + koct * 8];
#pragma unroll
        for (int cf = 0; cf < 12; ++cf) {
            short8 bfg = *(const short8*)&sm.ab.B[cur][(cf * 16 + l16) * 40 + koct * 8];
            acc[0][cf] = __builtin_amdgcn_mfma_f32_16x16x32_bf16(af[0], bfg, acc[0][cf], 0, 0, 0);
            acc[1][cf] = __builtin_amdgcn_mfma_f32_16x16x32_bf16(af[1], bfg, acc[1][cf], 0, 0, 0);
        }

        if (s + 1 < NSTEPS) STORE((s + 1) & 1);
        __syncthreads();
    }

    // --- epilogue: aggH (cols 128..191) fp32 direct ---
#pragma unroll
    for (int rb = 0; rb < 2; ++rb)
#pragma unroll
        for (int cf = 8; cf < 12; ++cf)
#pragma unroll
            for (int reg = 0; reg < 4; ++reg) {
                const int r = row0 + w * 32 + rb * 16 + koct * 4 + reg;
                const int c = (cf - 8) * 16 + l16;
                if (r < N_NODES) aggH[(size_t)r * HID + c] = acc[rb][cf][reg];
            }

    // --- epilogue: xw01 (cols 0..127) -> interleaved bf16 via LDS, 2 passes ---
    for (int p = 0; p < 2; ++p) {
        __syncthreads();
        if ((w >> 1) == p) {
            const int wl = w & 1;
#pragma unroll
            for (int rb = 0; rb < 2; ++rb)
#pragma unroll
                for (int cf = 0; cf < 8; ++cf)
#pragma unroll
                    for (int reg = 0; reg < 4; ++reg) {
                        const int rloc = wl * 32 + rb * 16 + koct * 4 + reg;
                        const int cg = cf * 16 + l16;
                        const int idx = (cg < 64) ? (2 * cg) : (2 * cg - 127);
                        sm.O[rloc * 264 + idx] = f2bf(acc[rb][cf][reg]);
                    }
        }
        __syncthreads();
        const int row = tid >> 2, q = tid & 3;
        const int rg = row0 + p * 64 + row;
        if (rg < N_NODES) {
#pragma unroll
            for (int j = 0; j < 4; ++j) {
                uint4 v = *(const uint4*)&sm.O[row * 264 + q * 32 + j * 8];
                *(uint4*)&xw01[(size_t)rg * 128 + q * 32 + j * 8] = v;
            }
        }
    }
}

// ---------------------------------------------------------------------------
// AGG1: wave per node; lane = hidden dim. acc = aggH(root) + sum over edges.
// ---------------------------------------------------------------------------
__global__ __launch_bounds__(256) void agg1(
    const int* __restrict__ off, const int* __restrict__ cnt,
    const uint2* __restrict__ epk, const unsigned* __restrict__ xw01_u,
    float* __restrict__ aggH)
{
    const int n = blockIdx.x * 4 + (threadIdx.x >> 6);
    if (n >= N_NODES) return;
    const int d = threadIdx.x & 63;
    const int start = off[n];
    const int deg = cnt[n];

    float acc = aggH[(size_t)n * HID + d];
    for (int i = 0; i < deg; i += 4) {
        unsigned srcs[4];
        float w0[4], w1[4];
#pragma unroll
        for (int j = 0; j < 4; ++j) {
            const bool ok = (i + j) < deg;
            const int idx = ok ? (start + i + j) : start;
            const uint2 t = epk[idx];
            const float v = __builtin_bit_cast(float, t.y);
            srcs[j] = t.x;
            w0[j] = ok ? (1.f - v) : 0.f;
            w1[j] = ok ? v : 0.f;
        }
        unsigned g[4];
#pragma unroll
        for (int j = 0; j < 4; ++j) g[j] = xw01_u[(size_t)srcs[j] * 64 + d];
#pragma unroll
        for (int j = 0; j < 4; ++j) {
            acc += w0[j] * bf2f((unsigned short)(g[j] & 0xFFFF));
            acc += w1[j] * bf2f((unsigned short)(g[j] >> 16));
        }
    }
    aggH[(size_t)n * HID + d] = acc;
}

// ---------------------------------------------------------------------------
// K3: h = relu(aggH + b1); hw01 = packed bf16 {h@w2[0], h@w2[1]}; agg2 = h@root2.
// ---------------------------------------------------------------------------
__global__ __launch_bounds__(256) void k3_relu_gemm(
    const float* __restrict__ aggH, const float* __restrict__ b1,
    const float* __restrict__ w2, const float* __restrict__ root2,
    unsigned* __restrict__ hw01_u, float* __restrict__ agg2)
{
    __shared__ float Ws[3 * HID * NCLS];
    __shared__ float Hs[16][HID];

    const int tid = threadIdx.x;
    for (int i = tid; i < 2 * HID * NCLS; i += 256) Ws[i] = w2[i];
    for (int i = tid; i < HID * NCLS; i += 256) Ws[2 * HID * NCLS + i] = root2[i];

    const int n0 = blockIdx.x * 16;
    for (int i = tid; i < 16 * HID; i += 256) {
        const int nl = i >> 6, k = i & 63;
        const float h = aggH[(size_t)(n0 + nl) * HID + k] + b1[k];
        Hs[nl][k] = fmaxf(h, 0.f);
    }
    __syncthreads();

    const int nl = tid >> 4;
    const int c = tid & 15;
    float a0 = 0.f, a1 = 0.f, a2 = 0.f;
#pragma unroll
    for (int k = 0; k < HID; ++k) {
        const float h = Hs[nl][k];
        a0 += h * Ws[0 * HID * NCLS + k * NCLS + c];
        a1 += h * Ws[1 * HID * NCLS + k * NCLS + c];
        a2 += h * Ws[2 * HID * NCLS + k * NCLS + c];
    }
    const size_t o = (size_t)(n0 + nl) * NCLS + c;
    hw01_u[o] = pack2(f2bf(a0), f2bf(a1));
    agg2[o] = a2;
}

// ---------------------------------------------------------------------------
// AGG2 + log_softmax fused: 16 lanes per node, 16 nodes per block.
// ---------------------------------------------------------------------------
__global__ __launch_bounds__(256) void agg2_sm(
    const int* __restrict__ off, const int* __restrict__ cnt,
    const uint2* __restrict__ epk, const unsigned* __restrict__ hw01_u,
    const float* __restrict__ agg2, const float* __restrict__ b2,
    float* __restrict__ out)
{
    const int n = blockIdx.x * 16 + (threadIdx.x >> 4);
    const int c = threadIdx.x & 15;
    const int start = off[n];
    const int deg = cnt[n];

    float acc = agg2[(size_t)n * NCLS + c];
    for (int i = 0; i < deg; i += 4) {
        unsigned srcs[4];
        float w0[4], w1[4];
#pragma unroll
        for (int j = 0; j < 4; ++j) {
            const bool ok = (i + j) < deg;
            const int idx = ok ? (start + i + j) : start;
            const uint2 t = epk[idx];
            const float v = __builtin_bit_cast(float, t.y);
            srcs[j] = t.x;
            w0[j] = ok ? (1.f - v) : 0.f;
            w1[j] = ok ? v : 0.f;
        }
        unsigned g[4];
#pragma unroll
        for (int j = 0; j < 4; ++j) g[j] = hw01_u[(size_t)srcs[j] * NCLS + c];
#pragma unroll
        for (int j = 0; j < 4; ++j) {
            acc += w0[j] * bf2f((unsigned short)(g[j] & 0xFFFF));
            acc += w1[j] * bf2f((unsigned short)(g[j] >> 16));
        }
    }

    const float z = acc + b2[c];
    float m = z;
#pragma unroll
    for (int s = 1; s < 16; s <<= 1) m = fmaxf(m, __shfl_xor(m, s, 64));
    const float e = expf(z - m);
    float ssum = e;
#pragma unroll
    for (int s = 1; s < 16; s <<= 1) ssum += __shfl_xor(ssum, s, 64);
    out[(size_t)n * NCLS + c] = (z - m) - logf(ssum);
}

extern "C" void kernel_launch(void* const* d_in, const int* in_sizes, int n_in,
                              void* d_out, int out_size, void* d_ws, size_t ws_size,
                              hipStream_t stream) {
    const float* x = (const float*)d_in[0];
    const int* ei = (const int*)d_in[1];
    const float* ea = (const float*)d_in[2];
    const float* w1 = (const float*)d_in[3];
    const float* root1 = (const float*)d_in[4];
    const float* b1 = (const float*)d_in[5];
    const float* w2 = (const float*)d_in[6];
    const float* root2 = (const float*)d_in[7];
    const float* b2 = (const float*)d_in[8];
    float* out = (float*)d_out;

    char* ws = (char*)d_ws;
    unsigned short* xw01 = (unsigned short*)ws;                 // 25.6 MB
    float* aggH = (float*)(ws + 25600000);                      // 25.6 MB
    unsigned* hw01_u = (unsigned*)(ws + 51200000);              // 6.4 MB
    float* agg2 = (float*)(ws + 57600000);                      // 6.4 MB
    unsigned short* Bt = (unsigned short*)(ws + 64000000);      // 0.2 MB
    int* cnt = (int*)(ws + 64300000);                           // 0.4 MB
    int* off = (int*)(ws + 64800000);                           // 0.4 MB
    int* cursor = (int*)(ws + 65300000);                        // 0.4 MB
    int* bsum = (int*)(ws + 65800000);                          // 2 KB
    int* bsumoff = (int*)(ws + 65810000);                       // 2 KB
    uint2* epk = (uint2*)(ws + 65820000);                       // 12.8 MB

    // CSR build
    csr_zero<<<NB_SCAN, 256, 0, stream>>>(cnt);
    csr_hist<<<2048, 256, 0, stream>>>(ei, cnt);
    csr_scan1<<<NB_SCAN, 256, 0, stream>>>(cnt, off, bsum);
    csr_scan2<<<1, 512, 0, stream>>>(bsum, bsumoff);
    csr_scan3<<<NB_SCAN, 256, 0, stream>>>(off, bsumoff, cursor);
    csr_scatter<<<2048, 256, 0, stream>>>(ei, ea, cursor, epk);

    // layer 1
    k0_bt<<<192, 256, 0, stream>>>(w1, root1, Bt);
    k1_mfma<<<(N_NODES + 127) / 128, 256, 0, stream>>>(x, Bt, xw01, aggH);
    agg1<<<(N_NODES + 3) / 4, 256, 0, stream>>>(off, cnt, epk, (const unsigned*)xw01, aggH);

    // layer 2
    k3_relu_gemm<<<N_NODES / 16, 256, 0, stream>>>(aggH, b1, w2, root2, hw01_u, agg2);
    agg2_sm<<<N_NODES / 16, 256, 0, stream>>>(off, cnt, epk, hw01_u, agg2, b2, out);
}

// Round 5
// 387.228 us; speedup vs baseline: 1.1613x; 1.1613x over previous
//
#include <hip/hip_runtime.h>
#include <math.h>

#define N_NODES 100000
#define N_EDGES 1600000
#define IN_DIM 500
#define HID 64
#define NCLS 16
#define KP 512     // padded K for layer-1 GEMM
#define NSTEPS 16  // KP/32
#define NB_SCAN 391  // ceil(100000/256)
#define NPAD (NB_SCAN * 256)

typedef __attribute__((ext_vector_type(8))) short short8;
typedef __attribute__((ext_vector_type(4))) float f32x4;

__device__ __forceinline__ unsigned short f2bf(float f) {
    unsigned u = __builtin_bit_cast(unsigned, f);
    return (unsigned short)((u + 0x7FFFu + ((u >> 16) & 1u)) >> 16);
}
__device__ __forceinline__ float bf2f(unsigned short s) {
    unsigned u = ((unsigned)s) << 16;
    return __builtin_bit_cast(float, u);
}
__device__ __forceinline__ unsigned pack2(unsigned short a, unsigned short b) {
    return (unsigned)a | ((unsigned)b << 16);
}
// async global->LDS, 16B per lane; LDS dest is wave-uniform base + lane*16
__device__ __forceinline__ void gload16(const void* g, void* l) {
    __builtin_amdgcn_global_load_lds(
        (const __attribute__((address_space(1))) unsigned*)g,
        (__attribute__((address_space(3))) unsigned*)l, 16, 0, 0);
}

// ---------------------------------------------------------------------------
// K0: build Bt[192][512] bf16 = transpose of {w1[0], w1[1], root1}, zero-pad K.
// ---------------------------------------------------------------------------
__global__ __launch_bounds__(256) void k0_bt(
    const float* __restrict__ w1, const float* __restrict__ root1,
    unsigned short* __restrict__ Bt)
{
    const int b = blockIdx.x;  // 0..191
    const float* src;
    int c;
    if (b < 64)        { src = w1;                c = b; }
    else if (b < 128)  { src = w1 + IN_DIM * HID; c = b - 64; }
    else               { src = root1;             c = b - 128; }
    for (int k = threadIdx.x; k < KP; k += 256) {
        float v = (k < IN_DIM) ? src[k * HID + c] : 0.f;
        Bt[b * KP + k] = f2bf(v);
    }
}

// ---------------------------------------------------------------------------
// CSR build: zero, histogram, scan x3, scatter
// ---------------------------------------------------------------------------
__global__ __launch_bounds__(256) void csr_zero(int* __restrict__ cnt)
{
    const int i = blockIdx.x * 256 + threadIdx.x;
    if (i < NPAD) cnt[i] = 0;
}

__global__ __launch_bounds__(256) void csr_hist(
    const int* __restrict__ ei, int* __restrict__ cnt)
{
    for (int e = blockIdx.x * 256 + threadIdx.x; e < N_EDGES; e += gridDim.x * 256)
        atomicAdd(&cnt[ei[N_EDGES + e]], 1);
}

__global__ __launch_bounds__(256) void csr_scan1(
    const int* __restrict__ cnt, int* __restrict__ off, int* __restrict__ bsum)
{
    __shared__ int s[256];
    const int t = threadIdx.x;
    const int i = blockIdx.x * 256 + t;
    const int val = cnt[i];
    s[t] = val;
    for (int d = 1; d < 256; d <<= 1) {
        __syncthreads();
        int add = (t >= d) ? s[t - d] : 0;
        __syncthreads();
        s[t] += add;
    }
    __syncthreads();
    off[i] = s[t] - val;
    if (t == 255) bsum[blockIdx.x] = s[255];
}

__global__ __launch_bounds__(512) void csr_scan2(
    const int* __restrict__ bsum, int* __restrict__ bsumoff)
{
    __shared__ int s[512];
    const int t = threadIdx.x;
    const int val = (t < NB_SCAN) ? bsum[t] : 0;
    s[t] = val;
    for (int d = 1; d < 512; d <<= 1) {
        __syncthreads();
        int add = (t >= d) ? s[t - d] : 0;
        __syncthreads();
        s[t] += add;
    }
    __syncthreads();
    if (t < NB_SCAN) bsumoff[t] = s[t] - val;
}

__global__ __launch_bounds__(256) void csr_scan3(
    int* __restrict__ off, const int* __restrict__ bsumoff, int* __restrict__ cursor)
{
    const int i = blockIdx.x * 256 + threadIdx.x;
    const int o = off[i] + bsumoff[blockIdx.x];
    off[i] = o;
    cursor[i] = o;
}

__global__ __launch_bounds__(256) void csr_scatter(
    const int* __restrict__ ei, const float* __restrict__ ea,
    int* __restrict__ cursor, uint2* __restrict__ epk)
{
    for (int e = blockIdx.x * 256 + threadIdx.x; e < N_EDGES; e += gridDim.x * 256) {
        const int src = ei[e];
        const int dst = ei[N_EDGES + e];
        const float v = fminf(fmaxf(ea[e], 0.f), 1.f - 1e-6f);
        const int pos = atomicAdd(&cursor[dst], 1);
        epk[pos] = make_uint2((unsigned)src, __builtin_bit_cast(unsigned, v));
    }
}

// ---------------------------------------------------------------------------
// K1: bf16 MFMA GEMM, m97-style: global_load_lds staging (A fp32, B bf16),
// double-buffered LDS, one barrier per K-step, source-side XOR swizzle with
// matching XOR at ds_read (rule 21: same involution both sides).
// Tile: 64 rows x 192 cols, BK=32. 4 waves in 2x2: wave owns 32 rows x 96 cols.
// ---------------------------------------------------------------------------
union K1Smem {
    struct { float A[2][64 * 32]; unsigned short B[2][192 * 32]; } s;  // 16+24 KB
    unsigned short O[64 * 264];  // epilogue staging (33.8 KB < 40 KB)
};

__global__ __launch_bounds__(256) void k1_mfma(
    const float* __restrict__ x, const unsigned short* __restrict__ Bt,
    unsigned short* __restrict__ xw01, float* __restrict__ aggH)
{
    __shared__ K1Smem sm;

    const int tid = threadIdx.x;
    const int row0 = blockIdx.x * 64;
    const int w = tid >> 6;       // wave 0..3
    const int l = tid & 63;
    const int l16 = l & 15;
    const int koct = l >> 4;      // 0..3
    const int wr = w >> 1;        // row block (32 rows)
    const int wc = w & 1;         // col block (96 cols)

    f32x4 acc[2][6];
#pragma unroll
    for (int i = 0; i < 2; ++i)
#pragma unroll
        for (int j = 0; j < 6; ++j) acc[i][j] = (f32x4){0.f, 0.f, 0.f, 0.f};

    // --- stage-address precompute (lane-pure swizzles) ---
    // A: issue i covers rows (2w+i)*8..+8; lane l -> row wi*8+(l>>3), slot chunk l&7,
    //    fetches global chunk (l&7)^(l>>3)  [row&7 == l>>3]
    const int aJg4 = (((l & 7) ^ (l >> 3)) * 4);
    const float* aBase[2];
    int aLdsOff[2];
#pragma unroll
    for (int i = 0; i < 2; ++i) {
        const int rowl = (2 * w + i) * 8 + (l >> 3);
        int grow = row0 + rowl;
        if (grow > N_NODES - 1) grow = N_NODES - 1;  // clamp: finite garbage, B zero-pad kills it
        aBase[i] = x + (size_t)grow * IN_DIM;
        aLdsOff[i] = (2 * w + i) * 256;  // floats
    }
    // B: issue i covers cols (3w+i)*16..+16; lane l -> col wi*16+(l>>2), slot chunk l&3,
    //    fetches global chunk (l&3)^((l>>3)&3)
    const int bJg8 = (((l & 3) ^ ((l >> 3) & 3)) * 8);
    const unsigned short* bBase[3];
    int bLdsOff[3];
#pragma unroll
    for (int i = 0; i < 3; ++i) {
        const int coll = (3 * w + i) * 16 + (l >> 2);
        bBase[i] = Bt + (size_t)coll * KP + bJg8;
        bLdsOff[i] = (3 * w + i) * 512;  // ushorts
    }

    // read-side lane-pure swizzled chunk indices
    const int ja0 = ((2 * koct) ^ (l16 & 7)) * 4;       // fp32 offset of k-chunk g0
    const int ja1 = ((2 * koct + 1) ^ (l16 & 7)) * 4;   // fp32 offset of k-chunk g1
    const int jb = (koct ^ ((l16 >> 1) & 3)) * 8;       // ushort offset of B chunk

    // --- prologue: stage step 0 into buf 0 ---
    {
#pragma unroll
        for (int i = 0; i < 2; ++i) {
            int gk = aJg4; if (gk > IN_DIM - 4) gk = IN_DIM - 4;
            gload16(aBase[i] + gk, &sm.s.A[0][aLdsOff[i]]);
        }
#pragma unroll
        for (int i = 0; i < 3; ++i)
            gload16(bBase[i], &sm.s.B[0][bLdsOff[i]]);
    }
    __syncthreads();

    for (int s = 0; s < NSTEPS; ++s) {
        const int cur = s & 1;
        if (s < NSTEPS - 1) {
            const int k0n = (s + 1) * 32;
#pragma unroll
            for (int i = 0; i < 2; ++i) {
                int gk = k0n + aJg4; if (gk > IN_DIM - 4) gk = IN_DIM - 4;
                gload16(aBase[i] + gk, &sm.s.A[cur ^ 1][aLdsOff[i]]);
            }
#pragma unroll
            for (int i = 0; i < 3; ++i)
                gload16(bBase[i] + k0n, &sm.s.B[cur ^ 1][bLdsOff[i]]);
        }

        const float* LA = sm.s.A[cur];
        const unsigned short* LB = sm.s.B[cur];
        short8 af[2];
#pragma unroll
        for (int rb = 0; rb < 2; ++rb) {
            const int r = wr * 32 + rb * 16 + l16;
            f32x4 f0 = *(const f32x4*)&LA[r * 32 + ja0];
            f32x4 f1 = *(const f32x4*)&LA[r * 32 + ja1];
            short8 a;
            a[0] = (short)f2bf(f0[0]); a[1] = (short)f2bf(f0[1]);
            a[2] = (short)f2bf(f0[2]); a[3] = (short)f2bf(f0[3]);
            a[4] = (short)f2bf(f1[0]); a[5] = (short)f2bf(f1[1]);
            a[6] = (short)f2bf(f1[2]); a[7] = (short)f2bf(f1[3]);
            af[rb] = a;
        }
#pragma unroll
        for (int cf = 0; cf < 6; ++cf) {
            const int c = wc * 96 + cf * 16 + l16;
            short8 bfg = *(const short8*)&LB[c * 32 + jb];
            acc[0][cf] = __builtin_amdgcn_mfma_f32_16x16x32_bf16(af[0], bfg, acc[0][cf], 0, 0, 0);
            acc[1][cf] = __builtin_amdgcn_mfma_f32_16x16x32_bf16(af[1], bfg, acc[1][cf], 0, 0, 0);
        }
        __syncthreads();
    }

    // --- epilogue ---
    // cols >=128 -> aggH fp32 direct; cols <128 -> bf16 interleaved via LDS
#pragma unroll
    for (int rb = 0; rb < 2; ++rb)
#pragma unroll
        for (int cf = 0; cf < 6; ++cf) {
            const int cg = wc * 96 + cf * 16 + l16;
            if (96 * wc + cf * 16 < 128) {  // wave-uniform: xw columns
#pragma unroll
                for (int reg = 0; reg < 4; ++reg) {
                    const int rloc = wr * 32 + rb * 16 + koct * 4 + reg;
                    const int idx = (cg < 64) ? (2 * cg) : (2 * cg - 127);
                    sm.O[rloc * 264 + idx] = f2bf(acc[rb][cf][reg]);
                }
            } else {  // aggH columns
#pragma unroll
                for (int reg = 0; reg < 4; ++reg) {
                    const int r = row0 + wr * 32 + rb * 16 + koct * 4 + reg;
                    if (r < N_NODES) aggH[(size_t)r * HID + (cg - 128)] = acc[rb][cf][reg];
                }
            }
        }
    __syncthreads();
    {
        const int row = tid >> 2, q = tid & 3;
        const int rg = row0 + row;
        if (rg < N_NODES) {
#pragma unroll
            for (int j = 0; j < 4; ++j) {
                uint4 v = *(const uint4*)&sm.O[row * 264 + q * 32 + j * 8];
                *(uint4*)&xw01[(size_t)rg * 128 + q * 32 + j * 8] = v;
            }
        }
    }
}

// ---------------------------------------------------------------------------
// AGG1: wave per node; lane = hidden dim. acc = aggH(root) + sum over edges.
// ---------------------------------------------------------------------------
__global__ __launch_bounds__(256) void agg1(
    const int* __restrict__ off, const int* __restrict__ cnt,
    const uint2* __restrict__ epk, const unsigned* __restrict__ xw01_u,
    float* __restrict__ aggH)
{
    const int n = blockIdx.x * 4 + (threadIdx.x >> 6);
    if (n >= N_NODES) return;
    const int d = threadIdx.x & 63;
    const int start = off[n];
    const int deg = cnt[n];

    float acc = aggH[(size_t)n * HID + d];
    for (int i = 0; i < deg; i += 4) {
        unsigned srcs[4];
        float w0[4], w1[4];
#pragma unroll
        for (int j = 0; j < 4; ++j) {
            const bool ok = (i + j) < deg;
            const int idx = ok ? (start + i + j) : start;
            const uint2 t = epk[idx];
            const float v = __builtin_bit_cast(float, t.y);
            srcs[j] = t.x;
            w0[j] = ok ? (1.f - v) : 0.f;
            w1[j] = ok ? v : 0.f;
        }
        unsigned g[4];
#pragma unroll
        for (int j = 0; j < 4; ++j) g[j] = xw01_u[(size_t)srcs[j] * 64 + d];
#pragma unroll
        for (int j = 0; j < 4; ++j) {
            acc += w0[j] * bf2f((unsigned short)(g[j] & 0xFFFF));
            acc += w1[j] * bf2f((unsigned short)(g[j] >> 16));
        }
    }
    aggH[(size_t)n * HID + d] = acc;
}

// ---------------------------------------------------------------------------
// K3: h = relu(aggH + b1); hw01 = packed bf16 {h@w2[0], h@w2[1]}; agg2 = h@root2.
// ---------------------------------------------------------------------------
__global__ __launch_bounds__(256) void k3_relu_gemm(
    const float* __restrict__ aggH, const float* __restrict__ b1,
    const float* __restrict__ w2, const float* __restrict__ root2,
    unsigned* __restrict__ hw01_u, float* __restrict__ agg2)
{
    __shared__ float Ws[3 * HID * NCLS];
    __shared__ float Hs[16][HID];

    const int tid = threadIdx.x;
    for (int i = tid; i < 2 * HID * NCLS; i += 256) Ws[i] = w2[i];
    for (int i = tid; i < HID * NCLS; i += 256) Ws[2 * HID * NCLS + i] = root2[i];

    const int n0 = blockIdx.x * 16;
    for (int i = tid; i < 16 * HID; i += 256) {
        const int nl = i >> 6, k = i & 63;
        const float h = aggH[(size_t)(n0 + nl) * HID + k] + b1[k];
        Hs[nl][k] = fmaxf(h, 0.f);
    }
    __syncthreads();

    const int nl = tid >> 4;
    const int c = tid & 15;
    float a0 = 0.f, a1 = 0.f, a2 = 0.f;
#pragma unroll
    for (int k = 0; k < HID; ++k) {
        const float h = Hs[nl][k];
        a0 += h * Ws[0 * HID * NCLS + k * NCLS + c];
        a1 += h * Ws[1 * HID * NCLS + k * NCLS + c];
        a2 += h * Ws[2 * HID * NCLS + k * NCLS + c];
    }
    const size_t o = (size_t)(n0 + nl) * NCLS + c;
    hw01_u[o] = pack2(f2bf(a0), f2bf(a1));
    agg2[o] = a2;
}

// ---------------------------------------------------------------------------
// AGG2 + log_softmax fused: 16 lanes per node, 16 nodes per block.
// ---------------------------------------------------------------------------
__global__ __launch_bounds__(256) void agg2_sm(
    const int* __restrict__ off, const int* __restrict__ cnt,
    const uint2* __restrict__ epk, const unsigned* __restrict__ hw01_u,
    const float* __restrict__ agg2, const float* __restrict__ b2,
    float* __restrict__ out)
{
    const int n = blockIdx.x * 16 + (threadIdx.x >> 4);
    const int c = threadIdx.x & 15;
    const int start = off[n];
    const int deg = cnt[n];

    float acc = agg2[(size_t)n * NCLS + c];
    for (int i = 0; i < deg; i += 4) {
        unsigned srcs[4];
        float w0[4], w1[4];
#pragma unroll
        for (int j = 0; j < 4; ++j) {
            const bool ok = (i + j) < deg;
            const int idx = ok ? (start + i + j) : start;
            const uint2 t = epk[idx];
            const float v = __builtin_bit_cast(float, t.y);
            srcs[j] = t.x;
            w0[j] = ok ? (1.f - v) : 0.f;
            w1[j] = ok ? v : 0.f;
        }
        unsigned g[4];
#pragma unroll
        for (int j = 0; j < 4; ++j) g[j] = hw01_u[(size_t)srcs[j] * NCLS + c];
#pragma unroll
        for (int j = 0; j < 4; ++j) {
            acc += w0[j] * bf2f((unsigned short)(g[j] & 0xFFFF));
            acc += w1[j] * bf2f((unsigned short)(g[j] >> 16));
        }
    }

    const float z = acc + b2[c];
    float m = z;
#pragma unroll
    for (int s = 1; s < 16; s <<= 1) m = fmaxf(m, __shfl_xor(m, s, 64));
    const float e = expf(z - m);
    float ssum = e;
#pragma unroll
    for (int s = 1; s < 16; s <<= 1) ssum += __shfl_xor(ssum, s, 64);
    out[(size_t)n * NCLS + c] = (z - m) - logf(ssum);
}

extern "C" void kernel_launch(void* const* d_in, const int* in_sizes, int n_in,
                              void* d_out, int out_size, void* d_ws, size_t ws_size,
                              hipStream_t stream) {
    const float* x = (const float*)d_in[0];
    const int* ei = (const int*)d_in[1];
    const float* ea = (const float*)d_in[2];
    const float* w1 = (const float*)d_in[3];
    const float* root1 = (const float*)d_in[4];
    const float* b1 = (const float*)d_in[5];
    const float* w2 = (const float*)d_in[6];
    const float* root2 = (const float*)d_in[7];
    const float* b2 = (const float*)d_in[8];
    float* out = (float*)d_out;

    char* ws = (char*)d_ws;
    unsigned short* xw01 = (unsigned short*)ws;                 // 25.6 MB
    float* aggH = (float*)(ws + 25600000);                      // 25.6 MB
    unsigned* hw01_u = (unsigned*)(ws + 51200000);              // 6.4 MB
    float* agg2 = (float*)(ws + 57600000);                      // 6.4 MB
    unsigned short* Bt = (unsigned short*)(ws + 64000000);      // 0.2 MB
    int* cnt = (int*)(ws + 64300000);                           // 0.4 MB
    int* off = (int*)(ws + 64800000);                           // 0.4 MB
    int* cursor = (int*)(ws + 65300000);                        // 0.4 MB
    int* bsum = (int*)(ws + 65800000);                          // 2 KB
    int* bsumoff = (int*)(ws + 65810000);                       // 2 KB
    uint2* epk = (uint2*)(ws + 65820000);                       // 12.8 MB

    // CSR build
    csr_zero<<<NB_SCAN, 256, 0, stream>>>(cnt);
    csr_hist<<<2048, 256, 0, stream>>>(ei, cnt);
    csr_scan1<<<NB_SCAN, 256, 0, stream>>>(cnt, off, bsum);
    csr_scan2<<<1, 512, 0, stream>>>(bsum, bsumoff);
    csr_scan3<<<NB_SCAN, 256, 0, stream>>>(off, bsumoff, cursor);
    csr_scatter<<<2048, 256, 0, stream>>>(ei, ea, cursor, epk);

    // layer 1
    k0_bt<<<192, 256, 0, stream>>>(w1, root1, Bt);
    k1_mfma<<<(N_NODES + 63) / 64, 256, 0, stream>>>(x, Bt, xw01, aggH);
    agg1<<<(N_NODES + 3) / 4, 256, 0, stream>>>(off, cnt, epk, (const unsigned*)xw01, aggH);

    // layer 2
    k3_relu_gemm<<<N_NODES / 16, 256, 0, stream>>>(aggH, b1, w2, root2, hw01_u, agg2);
    agg2_sm<<<N_NODES / 16, 256, 0, stream>>>(off, cnt, epk, hw01_u, agg2, b2, out);
}

// Round 6
// 386.721 us; speedup vs baseline: 1.1628x; 1.0013x over previous
//
#include <hip/hip_runtime.h>
#include <math.h>

#define N_NODES 100000
#define N_EDGES 1600000
#define IN_DIM 500
#define HID 64
#define NCLS 16
#define KP 512     // padded K for layer-1 GEMM
#define NSTEPS 16  // KP/32
#define NB_SCAN 391  // ceil(100000/256)
#define NPAD (NB_SCAN * 256)
#define CSTRIDE 16  // ints per counter: one 64B cacheline per dst (atomic contention fix)

typedef __attribute__((ext_vector_type(8))) short short8;
typedef __attribute__((ext_vector_type(4))) float f32x4;

__device__ __forceinline__ unsigned short f2bf(float f) {
    unsigned u = __builtin_bit_cast(unsigned, f);
    return (unsigned short)((u + 0x7FFFu + ((u >> 16) & 1u)) >> 16);
}
__device__ __forceinline__ float bf2f(unsigned short s) {
    unsigned u = ((unsigned)s) << 16;
    return __builtin_bit_cast(float, u);
}
__device__ __forceinline__ unsigned pack2(unsigned short a, unsigned short b) {
    return (unsigned)a | ((unsigned)b << 16);
}
// async global->LDS, 16B per lane; LDS dest is wave-uniform base + lane*16
__device__ __forceinline__ void gload16(const void* g, void* l) {
    __builtin_amdgcn_global_load_lds(
        (const __attribute__((address_space(1))) unsigned*)g,
        (__attribute__((address_space(3))) unsigned*)l, 16, 0, 0);
}

// ---------------------------------------------------------------------------
// K0: build Bt[192][512] bf16 = transpose of {w1[0], w1[1], root1}, zero-pad K.
// ---------------------------------------------------------------------------
__global__ __launch_bounds__(256) void k0_bt(
    const float* __restrict__ w1, const float* __restrict__ root1,
    unsigned short* __restrict__ Bt)
{
    const int b = blockIdx.x;  // 0..191
    const float* src;
    int c;
    if (b < 64)        { src = w1;                c = b; }
    else if (b < 128)  { src = w1 + IN_DIM * HID; c = b - 64; }
    else               { src = root1;             c = b - 128; }
    for (int k = threadIdx.x; k < KP; k += 256) {
        float v = (k < IN_DIM) ? src[k * HID + c] : 0.f;
        Bt[b * KP + k] = f2bf(v);
    }
}

// ---------------------------------------------------------------------------
// CSR build: zero, histogram, scan x3, scatter.
// P is the padded counter array (CSTRIDE ints per node = 1 cacheline):
//   phase 1 (hist): P[n*CSTRIDE] = in-degree
//   phase 2 (scan3): P[n*CSTRIDE] = start offset (becomes the scatter cursor)
// ---------------------------------------------------------------------------
__global__ __launch_bounds__(256) void csr_zero(int* __restrict__ P)
{
    const int i = blockIdx.x * 256 + threadIdx.x;
    if (i < NPAD * CSTRIDE) P[i] = 0;
}

__global__ __launch_bounds__(256) void csr_hist(
    const int* __restrict__ ei, int* __restrict__ P)
{
    for (int e = blockIdx.x * 256 + threadIdx.x; e < N_EDGES; e += gridDim.x * 256)
        atomicAdd(&P[ei[N_EDGES + e] * CSTRIDE], 1);
}

__global__ __launch_bounds__(256) void csr_scan1(
    const int* __restrict__ P, int* __restrict__ off, int* __restrict__ bsum)
{
    __shared__ int s[256];
    const int t = threadIdx.x;
    const int i = blockIdx.x * 256 + t;
    const int val = P[i * CSTRIDE];
    s[t] = val;
    for (int d = 1; d < 256; d <<= 1) {
        __syncthreads();
        int add = (t >= d) ? s[t - d] : 0;
        __syncthreads();
        s[t] += add;
    }
    __syncthreads();
    off[i] = s[t] - val;
    if (t == 255) bsum[blockIdx.x] = s[255];
}

__global__ __launch_bounds__(512) void csr_scan2(
    const int* __restrict__ bsum, int* __restrict__ bsumoff)
{
    __shared__ int s[512];
    const int t = threadIdx.x;
    const int val = (t < NB_SCAN) ? bsum[t] : 0;
    s[t] = val;
    for (int d = 1; d < 512; d <<= 1) {
        __syncthreads();
        int add = (t >= d) ? s[t - d] : 0;
        __syncthreads();
        s[t] += add;
    }
    __syncthreads();
    if (t < NB_SCAN) bsumoff[t] = s[t] - val;
}

__global__ __launch_bounds__(256) void csr_scan3(
    int* __restrict__ off, const int* __restrict__ bsumoff, int* __restrict__ P)
{
    const int i = blockIdx.x * 256 + threadIdx.x;
    const int o = off[i] + bsumoff[blockIdx.x];
    off[i] = o;
    P[i * CSTRIDE] = o;  // becomes the scatter cursor
}

__global__ __launch_bounds__(256) void csr_scatter(
    const int* __restrict__ ei, const float* __restrict__ ea,
    int* __restrict__ P, uint2* __restrict__ epk)
{
    for (int e = blockIdx.x * 256 + threadIdx.x; e < N_EDGES; e += gridDim.x * 256) {
        const int src = ei[e];
        const int dst = ei[N_EDGES + e];
        const float v = fminf(fmaxf(ea[e], 0.f), 1.f - 1e-6f);
        const int pos = atomicAdd(&P[dst * CSTRIDE], 1);
        epk[pos] = make_uint2((unsigned)src, __builtin_bit_cast(unsigned, v));
    }
}

// ---------------------------------------------------------------------------
// K1: bf16 MFMA GEMM, m97-style: global_load_lds staging (A fp32, B bf16),
// double-buffered LDS, one barrier per K-step, source-side XOR swizzle with
// matching XOR at ds_read (rule 21: same involution both sides).
// Tile: 64 rows x 192 cols, BK=32. 4 waves in 2x2: wave owns 32 rows x 96 cols.
// ---------------------------------------------------------------------------
union K1Smem {
    struct { float A[2][64 * 32]; unsigned short B[2][192 * 32]; } s;  // 16+24 KB
    unsigned short O[64 * 264];  // epilogue staging (33.8 KB < 40 KB)
};

__global__ __launch_bounds__(256) void k1_mfma(
    const float* __restrict__ x, const unsigned short* __restrict__ Bt,
    unsigned short* __restrict__ xw01, float* __restrict__ aggH)
{
    __shared__ K1Smem sm;

    const int tid = threadIdx.x;
    const int row0 = blockIdx.x * 64;
    const int w = tid >> 6;       // wave 0..3
    const int l = tid & 63;
    const int l16 = l & 15;
    const int koct = l >> 4;      // 0..3
    const int wr = w >> 1;        // row block (32 rows)
    const int wc = w & 1;         // col block (96 cols)

    f32x4 acc[2][6];
#pragma unroll
    for (int i = 0; i < 2; ++i)
#pragma unroll
        for (int j = 0; j < 6; ++j) acc[i][j] = (f32x4){0.f, 0.f, 0.f, 0.f};

    const int aJg4 = (((l & 7) ^ (l >> 3)) * 4);
    const float* aBase[2];
    int aLdsOff[2];
#pragma unroll
    for (int i = 0; i < 2; ++i) {
        const int rowl = (2 * w + i) * 8 + (l >> 3);
        int grow = row0 + rowl;
        if (grow > N_NODES - 1) grow = N_NODES - 1;
        aBase[i] = x + (size_t)grow * IN_DIM;
        aLdsOff[i] = (2 * w + i) * 256;  // floats
    }
    const int bJg8 = (((l & 3) ^ ((l >> 3) & 3)) * 8);
    const unsigned short* bBase[3];
    int bLdsOff[3];
#pragma unroll
    for (int i = 0; i < 3; ++i) {
        const int coll = (3 * w + i) * 16 + (l >> 2);
        bBase[i] = Bt + (size_t)coll * KP + bJg8;
        bLdsOff[i] = (3 * w + i) * 512;  // ushorts
    }

    const int ja0 = ((2 * koct) ^ (l16 & 7)) * 4;
    const int ja1 = ((2 * koct + 1) ^ (l16 & 7)) * 4;
    const int jb = (koct ^ ((l16 >> 1) & 3)) * 8;

    {
#pragma unroll
        for (int i = 0; i < 2; ++i) {
            int gk = aJg4; if (gk > IN_DIM - 4) gk = IN_DIM - 4;
            gload16(aBase[i] + gk, &sm.s.A[0][aLdsOff[i]]);
        }
#pragma unroll
        for (int i = 0; i < 3; ++i)
            gload16(bBase[i], &sm.s.B[0][bLdsOff[i]]);
    }
    __syncthreads();

    for (int s = 0; s < NSTEPS; ++s) {
        const int cur = s & 1;
        if (s < NSTEPS - 1) {
            const int k0n = (s + 1) * 32;
#pragma unroll
            for (int i = 0; i < 2; ++i) {
                int gk = k0n + aJg4; if (gk > IN_DIM - 4) gk = IN_DIM - 4;
                gload16(aBase[i] + gk, &sm.s.A[cur ^ 1][aLdsOff[i]]);
            }
#pragma unroll
            for (int i = 0; i < 3; ++i)
                gload16(bBase[i] + k0n, &sm.s.B[cur ^ 1][bLdsOff[i]]);
        }

        const float* LA = sm.s.A[cur];
        const unsigned short* LB = sm.s.B[cur];
        short8 af[2];
#pragma unroll
        for (int rb = 0; rb < 2; ++rb) {
            const int r = wr * 32 + rb * 16 + l16;
            f32x4 f0 = *(const f32x4*)&LA[r * 32 + ja0];
            f32x4 f1 = *(const f32x4*)&LA[r * 32 + ja1];
            short8 a;
            a[0] = (short)f2bf(f0[0]); a[1] = (short)f2bf(f0[1]);
            a[2] = (short)f2bf(f0[2]); a[3] = (short)f2bf(f0[3]);
            a[4] = (short)f2bf(f1[0]); a[5] = (short)f2bf(f1[1]);
            a[6] = (short)f2bf(f1[2]); a[7] = (short)f2bf(f1[3]);
            af[rb] = a;
        }
#pragma unroll
        for (int cf = 0; cf < 6; ++cf) {
            const int c = wc * 96 + cf * 16 + l16;
            short8 bfg = *(const short8*)&LB[c * 32 + jb];
            acc[0][cf] = __builtin_amdgcn_mfma_f32_16x16x32_bf16(af[0], bfg, acc[0][cf], 0, 0, 0);
            acc[1][cf] = __builtin_amdgcn_mfma_f32_16x16x32_bf16(af[1], bfg, acc[1][cf], 0, 0, 0);
        }
        __syncthreads();
    }

#pragma unroll
    for (int rb = 0; rb < 2; ++rb)
#pragma unroll
        for (int cf = 0; cf < 6; ++cf) {
            const int cg = wc * 96 + cf * 16 + l16;
            if (96 * wc + cf * 16 < 128) {
#pragma unroll
                for (int reg = 0; reg < 4; ++reg) {
                    const int rloc = wr * 32 + rb * 16 + koct * 4 + reg;
                    const int idx = (cg < 64) ? (2 * cg) : (2 * cg - 127);
                    sm.O[rloc * 264 + idx] = f2bf(acc[rb][cf][reg]);
                }
            } else {
#pragma unroll
                for (int reg = 0; reg < 4; ++reg) {
                    const int r = row0 + wr * 32 + rb * 16 + koct * 4 + reg;
                    if (r < N_NODES) aggH[(size_t)r * HID + (cg - 128)] = acc[rb][cf][reg];
                }
            }
        }
    __syncthreads();
    {
        const int row = tid >> 2, q = tid & 3;
        const int rg = row0 + row;
        if (rg < N_NODES) {
#pragma unroll
            for (int j = 0; j < 4; ++j) {
                uint4 v = *(const uint4*)&sm.O[row * 264 + q * 32 + j * 8];
                *(uint4*)&xw01[(size_t)rg * 128 + q * 32 + j * 8] = v;
            }
        }
    }
}

// ---------------------------------------------------------------------------
// AGG1: wave per node; lane = hidden dim. acc = aggH(root) + sum over edges.
// ---------------------------------------------------------------------------
__global__ __launch_bounds__(256) void agg1(
    const int* __restrict__ off, const uint2* __restrict__ epk,
    const unsigned* __restrict__ xw01_u, float* __restrict__ aggH)
{
    const int n = blockIdx.x * 4 + (threadIdx.x >> 6);
    if (n >= N_NODES) return;
    const int d = threadIdx.x & 63;
    const int start = off[n];
    const int deg = off[n + 1] - start;

    float acc = aggH[(size_t)n * HID + d];
    for (int i = 0; i < deg; i += 4) {
        unsigned srcs[4];
        float w0[4], w1[4];
#pragma unroll
        for (int j = 0; j < 4; ++j) {
            const bool ok = (i + j) < deg;
            const int idx = ok ? (start + i + j) : start;
            const uint2 t = epk[idx];
            const float v = __builtin_bit_cast(float, t.y);
            srcs[j] = t.x;
            w0[j] = ok ? (1.f - v) : 0.f;
            w1[j] = ok ? v : 0.f;
        }
        unsigned g[4];
#pragma unroll
        for (int j = 0; j < 4; ++j) g[j] = xw01_u[(size_t)srcs[j] * 64 + d];
#pragma unroll
        for (int j = 0; j < 4; ++j) {
            acc += w0[j] * bf2f((unsigned short)(g[j] & 0xFFFF));
            acc += w1[j] * bf2f((unsigned short)(g[j] >> 16));
        }
    }
    aggH[(size_t)n * HID + d] = acc;
}

// ---------------------------------------------------------------------------
// K3: h = relu(aggH + b1); hw01 = packed bf16 {h@w2[0], h@w2[1]}; agg2 = h@root2.
// ---------------------------------------------------------------------------
__global__ __launch_bounds__(256) void k3_relu_gemm(
    const float* __restrict__ aggH, const float* __restrict__ b1,
    const float* __restrict__ w2, const float* __restrict__ root2,
    unsigned* __restrict__ hw01_u, float* __restrict__ agg2)
{
    __shared__ float Ws[3 * HID * NCLS];
    __shared__ float Hs[16][HID];

    const int tid = threadIdx.x;
    for (int i = tid; i < 2 * HID * NCLS; i += 256) Ws[i] = w2[i];
    for (int i = tid; i < HID * NCLS; i += 256) Ws[2 * HID * NCLS + i] = root2[i];

    const int n0 = blockIdx.x * 16;
    for (int i = tid; i < 16 * HID; i += 256) {
        const int nl = i >> 6, k = i & 63;
        const float h = aggH[(size_t)(n0 + nl) * HID + k] + b1[k];
        Hs[nl][k] = fmaxf(h, 0.f);
    }
    __syncthreads();

    const int nl = tid >> 4;
    const int c = tid & 15;
    float a0 = 0.f, a1 = 0.f, a2 = 0.f;
#pragma unroll
    for (int k = 0; k < HID; ++k) {
        const float h = Hs[nl][k];
        a0 += h * Ws[0 * HID * NCLS + k * NCLS + c];
        a1 += h * Ws[1 * HID * NCLS + k * NCLS + c];
        a2 += h * Ws[2 * HID * NCLS + k * NCLS + c];
    }
    const size_t o = (size_t)(n0 + nl) * NCLS + c;
    hw01_u[o] = pack2(f2bf(a0), f2bf(a1));
    agg2[o] = a2;
}

// ---------------------------------------------------------------------------
// AGG2 + log_softmax fused: 16 lanes per node, 16 nodes per block.
// ---------------------------------------------------------------------------
__global__ __launch_bounds__(256) void agg2_sm(
    const int* __restrict__ off, const uint2* __restrict__ epk,
    const unsigned* __restrict__ hw01_u, const float* __restrict__ agg2,
    const float* __restrict__ b2, float* __restrict__ out)
{
    const int n = blockIdx.x * 16 + (threadIdx.x >> 4);
    const int c = threadIdx.x & 15;
    const int start = off[n];
    const int deg = off[n + 1] - start;

    float acc = agg2[(size_t)n * NCLS + c];
    for (int i = 0; i < deg; i += 4) {
        unsigned srcs[4];
        float w0[4], w1[4];
#pragma unroll
        for (int j = 0; j < 4; ++j) {
            const bool ok = (i + j) < deg;
            const int idx = ok ? (start + i + j) : start;
            const uint2 t = epk[idx];
            const float v = __builtin_bit_cast(float, t.y);
            srcs[j] = t.x;
            w0[j] = ok ? (1.f - v) : 0.f;
            w1[j] = ok ? v : 0.f;
        }
        unsigned g[4];
#pragma unroll
        for (int j = 0; j < 4; ++j) g[j] = hw01_u[(size_t)srcs[j] * NCLS + c];
#pragma unroll
        for (int j = 0; j < 4; ++j) {
            acc += w0[j] * bf2f((unsigned short)(g[j] & 0xFFFF));
            acc += w1[j] * bf2f((unsigned short)(g[j] >> 16));
        }
    }

    const float z = acc + b2[c];
    float m = z;
#pragma unroll
    for (int s = 1; s < 16; s <<= 1) m = fmaxf(m, __shfl_xor(m, s, 64));
    const float e = expf(z - m);
    float ssum = e;
#pragma unroll
    for (int s = 1; s < 16; s <<= 1) ssum += __shfl_xor(ssum, s, 64);
    out[(size_t)n * NCLS + c] = (z - m) - logf(ssum);
}

extern "C" void kernel_launch(void* const* d_in, const int* in_sizes, int n_in,
                              void* d_out, int out_size, void* d_ws, size_t ws_size,
                              hipStream_t stream) {
    const float* x = (const float*)d_in[0];
    const int* ei = (const int*)d_in[1];
    const float* ea = (const float*)d_in[2];
    const float* w1 = (const float*)d_in[3];
    const float* root1 = (const float*)d_in[4];
    const float* b1 = (const float*)d_in[5];
    const float* w2 = (const float*)d_in[6];
    const float* root2 = (const float*)d_in[7];
    const float* b2 = (const float*)d_in[8];
    float* out = (float*)d_out;

    char* ws = (char*)d_ws;
    unsigned short* xw01 = (unsigned short*)ws;                 // 25.6 MB
    float* aggH = (float*)(ws + 25600000);                      // 25.6 MB
    unsigned* hw01_u = (unsigned*)(ws + 51200000);              // 6.4 MB
    float* agg2 = (float*)(ws + 57600000);                      // 6.4 MB
    unsigned short* Bt = (unsigned short*)(ws + 64000000);      // 0.2 MB
    int* off = (int*)(ws + 64300000);                           // 0.4 MB (NPAD)
    int* bsum = (int*)(ws + 65100000);                          // 2 KB
    int* bsumoff = (int*)(ws + 65110000);                       // 2 KB
    int* P = (int*)(ws + 65120000);                             // 6.4 MB padded counters
    uint2* epk = (uint2*)(ws + 71530000);                       // 12.8 MB -> ~84.3 MB

    // CSR build (padded counters: 1 cacheline per dst)
    csr_zero<<<(NPAD * CSTRIDE) / 256, 256, 0, stream>>>(P);
    csr_hist<<<2048, 256, 0, stream>>>(ei, P);
    csr_scan1<<<NB_SCAN, 256, 0, stream>>>(P, off, bsum);
    csr_scan2<<<1, 512, 0, stream>>>(bsum, bsumoff);
    csr_scan3<<<NB_SCAN, 256, 0, stream>>>(off, bsumoff, P);
    csr_scatter<<<2048, 256, 0, stream>>>(ei, ea, P, epk);

    // layer 1
    k0_bt<<<192, 256, 0, stream>>>(w1, root1, Bt);
    k1_mfma<<<(N_NODES + 63) / 64, 256, 0, stream>>>(x, Bt, xw01, aggH);
    agg1<<<(N_NODES + 3) / 4, 256, 0, stream>>>(off, epk, (const unsigned*)xw01, aggH);

    // layer 2
    k3_relu_gemm<<<N_NODES / 16, 256, 0, stream>>>(aggH, b1, w2, root2, hw01_u, agg2);
    agg2_sm<<<N_NODES / 16, 256, 0, stream>>>(off, epk, hw01_u, agg2, b2, out);
}

// Round 7
// 359.762 us; speedup vs baseline: 1.2500x; 1.0749x over previous
//
#include <hip/hip_runtime.h>
#include <math.h>

#define N_NODES 100000
#define N_EDGES 1600000
#define IN_DIM 500
#define HID 64
#define NCLS 16
#define KP 512     // padded K for layer-1 GEMM
#define NSTEPS 16  // KP/32
#define NB_SCAN 391  // ceil(100000/256)
#define NPAD (NB_SCAN * 256)
#define CSTRIDE 16   // padded cursor stride (ints)
#define NBUK 391     // buckets of 256 dsts: bucket = dst >> 8 (max 99999>>8 = 390)
#define EPB 4096     // edges per csr_bucket block
#define PLACE_CAP 7424  // max staged records in csr_place LDS path (59.4 KB)

typedef __attribute__((ext_vector_type(8))) short short8;
typedef __attribute__((ext_vector_type(4))) float f32x4;

__device__ __forceinline__ unsigned short f2bf(float f) {
    unsigned u = __builtin_bit_cast(unsigned, f);
    return (unsigned short)((u + 0x7FFFu + ((u >> 16) & 1u)) >> 16);
}
__device__ __forceinline__ float bf2f(unsigned short s) {
    unsigned u = ((unsigned)s) << 16;
    return __builtin_bit_cast(float, u);
}
__device__ __forceinline__ unsigned pack2(unsigned short a, unsigned short b) {
    return (unsigned)a | ((unsigned)b << 16);
}
// async global->LDS, 16B per lane; LDS dest is wave-uniform base + lane*16
__device__ __forceinline__ void gload16(const void* g, void* l) {
    __builtin_amdgcn_global_load_lds(
        (const __attribute__((address_space(1))) unsigned*)g,
        (__attribute__((address_space(3))) unsigned*)l, 16, 0, 0);
}

// ---------------------------------------------------------------------------
// K0: build Bt[192][512] bf16 = transpose of {w1[0], w1[1], root1}, zero-pad K.
// ---------------------------------------------------------------------------
__global__ __launch_bounds__(256) void k0_bt(
    const float* __restrict__ w1, const float* __restrict__ root1,
    unsigned short* __restrict__ Bt)
{
    const int b = blockIdx.x;  // 0..191
    const float* src;
    int c;
    if (b < 64)        { src = w1;                c = b; }
    else if (b < 128)  { src = w1 + IN_DIM * HID; c = b - 64; }
    else               { src = root1;             c = b - 128; }
    for (int k = threadIdx.x; k < KP; k += 256) {
        float v = (k < IN_DIM) ? src[k * HID + c] : 0.f;
        Bt[b * KP + k] = f2bf(v);
    }
}

// ---------------------------------------------------------------------------
// CSR build: zero, histogram, scan x3, then 2-level bucketed counting sort.
// ---------------------------------------------------------------------------
__global__ __launch_bounds__(256) void csr_zero(int* __restrict__ P)
{
    const int i = blockIdx.x * 256 + threadIdx.x;
    if (i < NPAD * CSTRIDE) P[i] = 0;
}

__global__ __launch_bounds__(256) void csr_hist(
    const int* __restrict__ ei, int* __restrict__ P)
{
    for (int e = blockIdx.x * 256 + threadIdx.x; e < N_EDGES; e += gridDim.x * 256)
        atomicAdd(&P[ei[N_EDGES + e] * CSTRIDE], 1);  // no return value -> fast
}

__global__ __launch_bounds__(256) void csr_scan1(
    const int* __restrict__ P, int* __restrict__ off, int* __restrict__ bsum)
{
    __shared__ int s[256];
    const int t = threadIdx.x;
    const int i = blockIdx.x * 256 + t;
    const int val = P[i * CSTRIDE];
    s[t] = val;
    for (int d = 1; d < 256; d <<= 1) {
        __syncthreads();
        int add = (t >= d) ? s[t - d] : 0;
        __syncthreads();
        s[t] += add;
    }
    __syncthreads();
    off[i] = s[t] - val;
    if (t == 255) bsum[blockIdx.x] = s[255];
}

__global__ __launch_bounds__(512) void csr_scan2(
    const int* __restrict__ bsum, int* __restrict__ bsumoff)
{
    __shared__ int s[512];
    const int t = threadIdx.x;
    const int val = (t < NB_SCAN) ? bsum[t] : 0;
    s[t] = val;
    for (int d = 1; d < 512; d <<= 1) {
        __syncthreads();
        int add = (t >= d) ? s[t - d] : 0;
        __syncthreads();
        s[t] += add;
    }
    __syncthreads();
    if (t < NB_SCAN) bsumoff[t] = s[t] - val;
}

__global__ __launch_bounds__(256) void csr_scan3(
    int* __restrict__ off, const int* __restrict__ bsumoff, int* __restrict__ P)
{
    const int i = blockIdx.x * 256 + threadIdx.x;
    const int o = off[i] + bsumoff[blockIdx.x];
    off[i] = o;
    P[i * CSTRIDE] = o;  // per-dst cursor (fallback path only)
}

// bucket cursors: bkcur[b] = off[b*256]
__global__ __launch_bounds__(512) void csr_binit(
    const int* __restrict__ off, int* __restrict__ bkcur)
{
    const int b = threadIdx.x;
    if (b < NBUK) bkcur[b] = off[b << 8];
}

// Phase 1: scatter edges into their 256-dst bucket region (arbitrary order
// within bucket). Record: x = src, y = (dstlow<<24) | v_fixed24.
// One returning atomic per (block,bucket) instead of per edge.
__global__ __launch_bounds__(256) void csr_bucket(
    const int* __restrict__ ei, const float* __restrict__ ea,
    int* __restrict__ bkcur, uint2* __restrict__ epk)
{
    __shared__ int hcnt[NBUK];
    __shared__ int hbase[NBUK];

    const int tid = threadIdx.x;
    const int start = blockIdx.x * EPB;
    const int eend = min(start + EPB, N_EDGES);

    for (int i = tid; i < NBUK; i += 256) hcnt[i] = 0;
    __syncthreads();

#pragma unroll
    for (int j = 0; j < EPB / 256; ++j) {
        const int e = start + j * 256 + tid;
        if (e < eend) atomicAdd(&hcnt[ei[N_EDGES + e] >> 8], 1);
    }
    __syncthreads();

    for (int b = tid; b < NBUK; b += 256) {
        const int c = hcnt[b];
        hbase[b] = c ? atomicAdd(&bkcur[b], c) : 0;
    }
    __syncthreads();
    for (int i = tid; i < NBUK; i += 256) hcnt[i] = 0;
    __syncthreads();

#pragma unroll
    for (int j = 0; j < EPB / 256; ++j) {
        const int e = start + j * 256 + tid;
        if (e < eend) {
            const int src = ei[e];
            const int dst = ei[N_EDGES + e];
            const float v = fminf(fmaxf(ea[e], 0.f), 1.f - 1e-6f);
            const unsigned vq = (unsigned)(v * 16777216.0f);  // 24-bit fixed
            const int bk = dst >> 8;
            const int r = atomicAdd(&hcnt[bk], 1);
            epk[hbase[bk] + r] =
                make_uint2((unsigned)src, ((unsigned)(dst & 255) << 24) | vq);
        }
    }
}

// Phase 2: within each bucket region, place records at exact CSR position
// off[dst]+rank (rank via LDS atomics). Stages region in LDS, rewrites in
// place with final record (src, v as float).
__global__ __launch_bounds__(256) void csr_place(
    const int* __restrict__ off, int* __restrict__ P, uint2* __restrict__ epk,
    uint2* __restrict__ tmp)
{
    __shared__ uint2 recs[PLACE_CAP];
    __shared__ int dcnt[256];

    const int b = blockIdx.x;
    const int tid = threadIdx.x;
    const int start = off[b << 8];
    const int end = (b == NBUK - 1) ? N_EDGES : off[(b + 1) << 8];
    const int cnt = end - start;

    if (cnt <= PLACE_CAP) {
        for (int i = tid; i < cnt; i += 256) recs[i] = epk[start + i];
        __syncthreads();
        for (int i = tid; i < 256; i += 256) dcnt[i] = 0;
        __syncthreads();
        for (int i = tid; i < cnt; i += 256) {
            const uint2 u = recs[i];
            const int dl = u.y >> 24;
            const float v = (float)(u.y & 0xFFFFFFu) * 5.9604644775390625e-8f;
            const int r = atomicAdd(&dcnt[dl], 1);
            epk[off[(b << 8) + dl] + r] =
                make_uint2(u.x, __builtin_bit_cast(unsigned, v));
        }
    } else {
        // pathological big bucket: copy out, then place via global cursors
        for (int i = tid; i < cnt; i += 256) tmp[start + i] = epk[start + i];
        __threadfence();
        __syncthreads();
        for (int i = tid; i < cnt; i += 256) {
            const uint2 u = tmp[start + i];
            const int dst = (b << 8) | (int)(u.y >> 24);
            const float v = (float)(u.y & 0xFFFFFFu) * 5.9604644775390625e-8f;
            const int pos = atomicAdd(&P[dst * CSTRIDE], 1);
            epk[pos] = make_uint2(u.x, __builtin_bit_cast(unsigned, v));
        }
    }
}

// ---------------------------------------------------------------------------
// K1: bf16 MFMA GEMM, global_load_lds staging (A fp32, B bf16), double-
// buffered LDS, one barrier per K-step, both-sides XOR swizzle.
// Tile: 64 rows x 192 cols, BK=32. 4 waves in 2x2.
// ---------------------------------------------------------------------------
union K1Smem {
    struct { float A[2][64 * 32]; unsigned short B[2][192 * 32]; } s;  // 40 KB
    unsigned short O[64 * 264];  // epilogue staging (33.8 KB)
};

__global__ __launch_bounds__(256) void k1_mfma(
    const float* __restrict__ x, const unsigned short* __restrict__ Bt,
    unsigned short* __restrict__ xw01, float* __restrict__ aggH)
{
    __shared__ K1Smem sm;

    const int tid = threadIdx.x;
    const int row0 = blockIdx.x * 64;
    const int w = tid >> 6;
    const int l = tid & 63;
    const int l16 = l & 15;
    const int koct = l >> 4;
    const int wr = w >> 1;
    const int wc = w & 1;

    f32x4 acc[2][6];
#pragma unroll
    for (int i = 0; i < 2; ++i)
#pragma unroll
        for (int j = 0; j < 6; ++j) acc[i][j] = (f32x4){0.f, 0.f, 0.f, 0.f};

    const int aJg4 = (((l & 7) ^ (l >> 3)) * 4);
    const float* aBase[2];
    int aLdsOff[2];
#pragma unroll
    for (int i = 0; i < 2; ++i) {
        const int rowl = (2 * w + i) * 8 + (l >> 3);
        int grow = row0 + rowl;
        if (grow > N_NODES - 1) grow = N_NODES - 1;
        aBase[i] = x + (size_t)grow * IN_DIM;
        aLdsOff[i] = (2 * w + i) * 256;  // floats
    }
    const int bJg8 = (((l & 3) ^ ((l >> 3) & 3)) * 8);
    const unsigned short* bBase[3];
    int bLdsOff[3];
#pragma unroll
    for (int i = 0; i < 3; ++i) {
        const int coll = (3 * w + i) * 16 + (l >> 2);
        bBase[i] = Bt + (size_t)coll * KP + bJg8;
        bLdsOff[i] = (3 * w + i) * 512;  // ushorts
    }

    const int ja0 = ((2 * koct) ^ (l16 & 7)) * 4;
    const int ja1 = ((2 * koct + 1) ^ (l16 & 7)) * 4;
    const int jb = (koct ^ ((l16 >> 1) & 3)) * 8;

    {
#pragma unroll
        for (int i = 0; i < 2; ++i) {
            int gk = aJg4; if (gk > IN_DIM - 4) gk = IN_DIM - 4;
            gload16(aBase[i] + gk, &sm.s.A[0][aLdsOff[i]]);
        }
#pragma unroll
        for (int i = 0; i < 3; ++i)
            gload16(bBase[i], &sm.s.B[0][bLdsOff[i]]);
    }
    __syncthreads();

    for (int s = 0; s < NSTEPS; ++s) {
        const int cur = s & 1;
        if (s < NSTEPS - 1) {
            const int k0n = (s + 1) * 32;
#pragma unroll
            for (int i = 0; i < 2; ++i) {
                int gk = k0n + aJg4; if (gk > IN_DIM - 4) gk = IN_DIM - 4;
                gload16(aBase[i] + gk, &sm.s.A[cur ^ 1][aLdsOff[i]]);
            }
#pragma unroll
            for (int i = 0; i < 3; ++i)
                gload16(bBase[i] + k0n, &sm.s.B[cur ^ 1][bLdsOff[i]]);
        }

        const float* LA = sm.s.A[cur];
        const unsigned short* LB = sm.s.B[cur];
        short8 af[2];
#pragma unroll
        for (int rb = 0; rb < 2; ++rb) {
            const int r = wr * 32 + rb * 16 + l16;
            f32x4 f0 = *(const f32x4*)&LA[r * 32 + ja0];
            f32x4 f1 = *(const f32x4*)&LA[r * 32 + ja1];
            short8 a;
            a[0] = (short)f2bf(f0[0]); a[1] = (short)f2bf(f0[1]);
            a[2] = (short)f2bf(f0[2]); a[3] = (short)f2bf(f0[3]);
            a[4] = (short)f2bf(f1[0]); a[5] = (short)f2bf(f1[1]);
            a[6] = (short)f2bf(f1[2]); a[7] = (short)f2bf(f1[3]);
            af[rb] = a;
        }
#pragma unroll
        for (int cf = 0; cf < 6; ++cf) {
            const int c = wc * 96 + cf * 16 + l16;
            short8 bfg = *(const short8*)&LB[c * 32 + jb];
            acc[0][cf] = __builtin_amdgcn_mfma_f32_16x16x32_bf16(af[0], bfg, acc[0][cf], 0, 0, 0);
            acc[1][cf] = __builtin_amdgcn_mfma_f32_16x16x32_bf16(af[1], bfg, acc[1][cf], 0, 0, 0);
        }
        __syncthreads();
    }

#pragma unroll
    for (int rb = 0; rb < 2; ++rb)
#pragma unroll
        for (int cf = 0; cf < 6; ++cf) {
            const int cg = wc * 96 + cf * 16 + l16;
            if (96 * wc + cf * 16 < 128) {
#pragma unroll
                for (int reg = 0; reg < 4; ++reg) {
                    const int rloc = wr * 32 + rb * 16 + koct * 4 + reg;
                    const int idx = (cg < 64) ? (2 * cg) : (2 * cg - 127);
                    sm.O[rloc * 264 + idx] = f2bf(acc[rb][cf][reg]);
                }
            } else {
#pragma unroll
                for (int reg = 0; reg < 4; ++reg) {
                    const int r = row0 + wr * 32 + rb * 16 + koct * 4 + reg;
                    if (r < N_NODES) aggH[(size_t)r * HID + (cg - 128)] = acc[rb][cf][reg];
                }
            }
        }
    __syncthreads();
    {
        const int row = tid >> 2, q = tid & 3;
        const int rg = row0 + row;
        if (rg < N_NODES) {
#pragma unroll
            for (int j = 0; j < 4; ++j) {
                uint4 v = *(const uint4*)&sm.O[row * 264 + q * 32 + j * 8];
                *(uint4*)&xw01[(size_t)rg * 128 + q * 32 + j * 8] = v;
            }
        }
    }
}

// ---------------------------------------------------------------------------
// AGG1: wave per node; lane = hidden dim. acc = aggH(root) + sum over edges.
// ---------------------------------------------------------------------------
__global__ __launch_bounds__(256) void agg1(
    const int* __restrict__ off, const uint2* __restrict__ epk,
    const unsigned* __restrict__ xw01_u, float* __restrict__ aggH)
{
    const int n = blockIdx.x * 4 + (threadIdx.x >> 6);
    if (n >= N_NODES) return;
    const int d = threadIdx.x & 63;
    const int start = off[n];
    const int deg = off[n + 1] - start;

    float acc = aggH[(size_t)n * HID + d];
    for (int i = 0; i < deg; i += 4) {
        unsigned srcs[4];
        float w0[4], w1[4];
#pragma unroll
        for (int j = 0; j < 4; ++j) {
            const bool ok = (i + j) < deg;
            const int idx = ok ? (start + i + j) : start;
            const uint2 t = epk[idx];
            const float v = __builtin_bit_cast(float, t.y);
            srcs[j] = t.x;
            w0[j] = ok ? (1.f - v) : 0.f;
            w1[j] = ok ? v : 0.f;
        }
        unsigned g[4];
#pragma unroll
        for (int j = 0; j < 4; ++j) g[j] = xw01_u[(size_t)srcs[j] * 64 + d];
#pragma unroll
        for (int j = 0; j < 4; ++j) {
            acc += w0[j] * bf2f((unsigned short)(g[j] & 0xFFFF));
            acc += w1[j] * bf2f((unsigned short)(g[j] >> 16));
        }
    }
    aggH[(size_t)n * HID + d] = acc;
}

// ---------------------------------------------------------------------------
// K3: h = relu(aggH + b1); hw01 = packed bf16 {h@w2[0], h@w2[1]}; agg2 = h@root2.
// ---------------------------------------------------------------------------
__global__ __launch_bounds__(256) void k3_relu_gemm(
    const float* __restrict__ aggH, const float* __restrict__ b1,
    const float* __restrict__ w2, const float* __restrict__ root2,
    unsigned* __restrict__ hw01_u, float* __restrict__ agg2)
{
    __shared__ float Ws[3 * HID * NCLS];
    __shared__ float Hs[16][HID];

    const int tid = threadIdx.x;
    for (int i = tid; i < 2 * HID * NCLS; i += 256) Ws[i] = w2[i];
    for (int i = tid; i < HID * NCLS; i += 256) Ws[2 * HID * NCLS + i] = root2[i];

    const int n0 = blockIdx.x * 16;
    for (int i = tid; i < 16 * HID; i += 256) {
        const int nl = i >> 6, k = i & 63;
        const float h = aggH[(size_t)(n0 + nl) * HID + k] + b1[k];
        Hs[nl][k] = fmaxf(h, 0.f);
    }
    __syncthreads();

    const int nl = tid >> 4;
    const int c = tid & 15;
    float a0 = 0.f, a1 = 0.f, a2 = 0.f;
#pragma unroll
    for (int k = 0; k < HID; ++k) {
        const float h = Hs[nl][k];
        a0 += h * Ws[0 * HID * NCLS + k * NCLS + c];
        a1 += h * Ws[1 * HID * NCLS + k * NCLS + c];
        a2 += h * Ws[2 * HID * NCLS + k * NCLS + c];
    }
    const size_t o = (size_t)(n0 + nl) * NCLS + c;
    hw01_u[o] = pack2(f2bf(a0), f2bf(a1));
    agg2[o] = a2;
}

// ---------------------------------------------------------------------------
// AGG2 + log_softmax fused: 16 lanes per node, 16 nodes per block.
// ---------------------------------------------------------------------------
__global__ __launch_bounds__(256) void agg2_sm(
    const int* __restrict__ off, const uint2* __restrict__ epk,
    const unsigned* __restrict__ hw01_u, const float* __restrict__ agg2,
    const float* __restrict__ b2, float* __restrict__ out)
{
    const int n = blockIdx.x * 16 + (threadIdx.x >> 4);
    const int c = threadIdx.x & 15;
    const int start = off[n];
    const int deg = off[n + 1] - start;

    float acc = agg2[(size_t)n * NCLS + c];
    for (int i = 0; i < deg; i += 4) {
        unsigned srcs[4];
        float w0[4], w1[4];
#pragma unroll
        for (int j = 0; j < 4; ++j) {
            const bool ok = (i + j) < deg;
            const int idx = ok ? (start + i + j) : start;
            const uint2 t = epk[idx];
            const float v = __builtin_bit_cast(float, t.y);
            srcs[j] = t.x;
            w0[j] = ok ? (1.f - v) : 0.f;
            w1[j] = ok ? v : 0.f;
        }
        unsigned g[4];
#pragma unroll
        for (int j = 0; j < 4; ++j) g[j] = hw01_u[(size_t)srcs[j] * NCLS + c];
#pragma unroll
        for (int j = 0; j < 4; ++j) {
            acc += w0[j] * bf2f((unsigned short)(g[j] & 0xFFFF));
            acc += w1[j] * bf2f((unsigned short)(g[j] >> 16));
        }
    }

    const float z = acc + b2[c];
    float m = z;
#pragma unroll
    for (int s = 1; s < 16; s <<= 1) m = fmaxf(m, __shfl_xor(m, s, 64));
    const float e = expf(z - m);
    float ssum = e;
#pragma unroll
    for (int s = 1; s < 16; s <<= 1) ssum += __shfl_xor(ssum, s, 64);
    out[(size_t)n * NCLS + c] = (z - m) - logf(ssum);
}

extern "C" void kernel_launch(void* const* d_in, const int* in_sizes, int n_in,
                              void* d_out, int out_size, void* d_ws, size_t ws_size,
                              hipStream_t stream) {
    const float* x = (const float*)d_in[0];
    const int* ei = (const int*)d_in[1];
    const float* ea = (const float*)d_in[2];
    const float* w1 = (const float*)d_in[3];
    const float* root1 = (const float*)d_in[4];
    const float* b1 = (const float*)d_in[5];
    const float* w2 = (const float*)d_in[6];
    const float* root2 = (const float*)d_in[7];
    const float* b2 = (const float*)d_in[8];
    float* out = (float*)d_out;

    char* ws = (char*)d_ws;
    unsigned short* xw01 = (unsigned short*)ws;                 // 25.6 MB (tmp overlay pre-k1)
    float* aggH = (float*)(ws + 25600000);                      // 25.6 MB
    unsigned* hw01_u = (unsigned*)(ws + 51200000);              // 6.4 MB
    float* agg2 = (float*)(ws + 57600000);                      // 6.4 MB
    unsigned short* Bt = (unsigned short*)(ws + 64000000);      // 0.2 MB
    int* off = (int*)(ws + 64300000);                           // 0.4 MB (NPAD ints)
    int* bsum = (int*)(ws + 64800000);                          // 1.6 KB
    int* bsumoff = (int*)(ws + 64810000);                       // 1.6 KB
    int* bkcur = (int*)(ws + 64820000);                         // 1.6 KB
    int* P = (int*)(ws + 64830000);                             // 6.4 MB padded cursors
    uint2* epk = (uint2*)(ws + 71240000);                       // 12.8 MB -> ~84 MB total
    uint2* tmp = (uint2*)xw01;  // fallback scratch; k1 writes xw01 only after csr_place

    // CSR build
    csr_zero<<<(NPAD * CSTRIDE) / 256, 256, 0, stream>>>(P);
    csr_hist<<<2048, 256, 0, stream>>>(ei, P);
    csr_scan1<<<NB_SCAN, 256, 0, stream>>>(P, off, bsum);
    csr_scan2<<<1, 512, 0, stream>>>(bsum, bsumoff);
    csr_scan3<<<NB_SCAN, 256, 0, stream>>>(off, bsumoff, P);
    csr_binit<<<1, 512, 0, stream>>>(off, bkcur);
    csr_bucket<<<(N_EDGES + EPB - 1) / EPB, 256, 0, stream>>>(ei, ea, bkcur, epk);
    csr_place<<<NBUK, 256, 0, stream>>>(off, P, epk, tmp);

    // layer 1
    k0_bt<<<192, 256, 0, stream>>>(w1, root1, Bt);
    k1_mfma<<<(N_NODES + 63) / 64, 256, 0, stream>>>(x, Bt, xw01, aggH);
    agg1<<<(N_NODES + 3) / 4, 256, 0, stream>>>(off, epk, (const unsigned*)xw01, aggH);

    // layer 2
    k3_relu_gemm<<<N_NODES / 16, 256, 0, stream>>>(aggH, b1, w2, root2, hw01_u, agg2);
    agg2_sm<<<N_NODES / 16, 256, 0, stream>>>(off, epk, hw01_u, agg2, b2, out);
}

// Round 8
// 302.964 us; speedup vs baseline: 1.4843x; 1.1875x over previous
//
#include <hip/hip_runtime.h>
#include <math.h>

#define N_NODES 100000
#define N_EDGES 1600000
#define IN_DIM 500
#define HID 64
#define NCLS 16
#define KP 512     // padded K for layer-1 GEMM
#define NSTEPS 16  // KP/32
#define NBUK 391     // buckets of 256 dsts: bucket = dst >> 8
#define NPAD (NBUK * 256)
#define EPB 4096     // edges per bucket-phase block

typedef __attribute__((ext_vector_type(8))) short short8;
typedef __attribute__((ext_vector_type(4))) float f32x4;

__device__ __forceinline__ unsigned short f2bf(float f) {
    unsigned u = __builtin_bit_cast(unsigned, f);
    return (unsigned short)((u + 0x7FFFu + ((u >> 16) & 1u)) >> 16);
}
__device__ __forceinline__ float bf2f(unsigned short s) {
    unsigned u = ((unsigned)s) << 16;
    return __builtin_bit_cast(float, u);
}
__device__ __forceinline__ unsigned pack2(unsigned short a, unsigned short b) {
    return (unsigned)a | ((unsigned)b << 16);
}
// async global->LDS, 16B per lane; LDS dest is wave-uniform base + lane*16
__device__ __forceinline__ void gload16(const void* g, void* l) {
    __builtin_amdgcn_global_load_lds(
        (const __attribute__((address_space(1))) unsigned*)g,
        (__attribute__((address_space(3))) unsigned*)l, 16, 0, 0);
}

// ---------------------------------------------------------------------------
// K0: build Bt[192][512] bf16 = transpose of {w1[0], w1[1], root1}, zero-pad K.
// ---------------------------------------------------------------------------
__global__ __launch_bounds__(256) void k0_bt(
    const float* __restrict__ w1, const float* __restrict__ root1,
    unsigned short* __restrict__ Bt)
{
    const int b = blockIdx.x;  // 0..191
    const float* src;
    int c;
    if (b < 64)        { src = w1;                c = b; }
    else if (b < 128)  { src = w1 + IN_DIM * HID; c = b - 64; }
    else               { src = root1;             c = b - 128; }
    for (int k = threadIdx.x; k < KP; k += 256) {
        float v = (k < IN_DIM) ? src[k * HID + c] : 0.f;
        Bt[b * KP + k] = f2bf(v);
    }
}

// ---------------------------------------------------------------------------
// CSR build, bucket-level only:
//   bzero -> bhist (LDS hist of 391 buckets) -> bscan (1 block) ->
//   bucket (rank-scatter into bucket regions) -> place (per-dst offsets + final sort)
// ---------------------------------------------------------------------------
__global__ __launch_bounds__(512) void csr_bzero(int* __restrict__ bkcnt)
{
    if (threadIdx.x < NBUK) bkcnt[threadIdx.x] = 0;
}

__global__ __launch_bounds__(256) void csr_bhist(
    const int* __restrict__ ei, int* __restrict__ bkcnt)
{
    __shared__ int h[NBUK];
    const int tid = threadIdx.x;
    for (int i = tid; i < NBUK; i += 256) h[i] = 0;
    __syncthreads();
    const int start = blockIdx.x * EPB;
    const int eend = min(start + EPB, N_EDGES);
#pragma unroll
    for (int j = 0; j < EPB / 256; ++j) {
        const int e = start + j * 256 + tid;
        if (e < eend) atomicAdd(&h[ei[N_EDGES + e] >> 8], 1);
    }
    __syncthreads();
    for (int i = tid; i < NBUK; i += 256)
        if (h[i]) atomicAdd(&bkcnt[i], h[i]);
}

__global__ __launch_bounds__(512) void csr_bscan(
    const int* __restrict__ bkcnt, int* __restrict__ bkoff, int* __restrict__ bkcur)
{
    __shared__ int s[512];
    const int t = threadIdx.x;
    const int val = (t < NBUK) ? bkcnt[t] : 0;
    s[t] = val;
    for (int d = 1; d < 512; d <<= 1) {
        __syncthreads();
        int add = (t >= d) ? s[t - d] : 0;
        __syncthreads();
        s[t] += add;
    }
    __syncthreads();
    if (t < NBUK) {
        const int o = s[t] - val;
        bkoff[t] = o;
        bkcur[t] = o;
    }
    if (t == NBUK - 1) bkoff[NBUK] = s[t];  // == N_EDGES
}

// Phase 1: scatter edges into their 256-dst bucket region (arbitrary order
// within bucket). Record: x = src, y = (dstlow<<24) | v_fixed24.
__global__ __launch_bounds__(256) void csr_bucket(
    const int* __restrict__ ei, const float* __restrict__ ea,
    int* __restrict__ bkcur, uint2* __restrict__ epk)
{
    __shared__ int hcnt[NBUK];
    __shared__ int hbase[NBUK];

    const int tid = threadIdx.x;
    const int start = blockIdx.x * EPB;
    const int eend = min(start + EPB, N_EDGES);

    for (int i = tid; i < NBUK; i += 256) hcnt[i] = 0;
    __syncthreads();

#pragma unroll
    for (int j = 0; j < EPB / 256; ++j) {
        const int e = start + j * 256 + tid;
        if (e < eend) atomicAdd(&hcnt[ei[N_EDGES + e] >> 8], 1);
    }
    __syncthreads();

    for (int b = tid; b < NBUK; b += 256) {
        const int c = hcnt[b];
        hbase[b] = c ? atomicAdd(&bkcur[b], c) : 0;
    }
    __syncthreads();
    for (int i = tid; i < NBUK; i += 256) hcnt[i] = 0;
    __syncthreads();

#pragma unroll
    for (int j = 0; j < EPB / 256; ++j) {
        const int e = start + j * 256 + tid;
        if (e < eend) {
            const int src = ei[e];
            const int dst = ei[N_EDGES + e];
            const float v = fminf(fmaxf(ea[e], 0.f), 1.f - 1e-6f);
            const unsigned vq = (unsigned)(v * 16777216.0f);  // 24-bit fixed
            const int bk = dst >> 8;
            const int r = atomicAdd(&hcnt[bk], 1);
            epk[hbase[bk] + r] =
                make_uint2((unsigned)src, ((unsigned)(dst & 255) << 24) | vq);
        }
    }
}

// Phase 2: per bucket, 2-pass (no staging): (a) LDS hist of 256 dsts + LDS
// scan -> write global off[]; (b) re-read records, rank via LDS atomics,
// write final (src, v_f32) to epkS at off[dst]+rank.
__global__ __launch_bounds__(256) void csr_place(
    const int* __restrict__ bkoff, const uint2* __restrict__ epk,
    uint2* __restrict__ epkS, int* __restrict__ off)
{
    __shared__ int hist[256];
    __shared__ int sc[256];
    __shared__ int cur[256];

    const int b = blockIdx.x;
    const int tid = threadIdx.x;
    const int start = bkoff[b];
    const int end = bkoff[b + 1];
    const int cnt = end - start;

    hist[tid] = 0;
    __syncthreads();
    for (int i = tid; i < cnt; i += 256)
        atomicAdd(&hist[epk[start + i].y >> 24], 1);
    __syncthreads();

    // inclusive scan of hist -> sc
    const int val = hist[tid];
    sc[tid] = val;
    for (int d = 1; d < 256; d <<= 1) {
        __syncthreads();
        int add = (tid >= d) ? sc[tid - d] : 0;
        __syncthreads();
        sc[tid] += add;
    }
    __syncthreads();
    const int mystart = start + sc[tid] - val;  // exclusive
    off[(b << 8) + tid] = mystart;
    cur[tid] = mystart;
    __syncthreads();

    for (int i = tid; i < cnt; i += 256) {
        const uint2 u = epk[start + i];
        const int dl = u.y >> 24;
        const float v = (float)(u.y & 0xFFFFFFu) * 5.9604644775390625e-8f;
        const int pos = atomicAdd(&cur[dl], 1);
        epkS[pos] = make_uint2(u.x, __builtin_bit_cast(unsigned, v));
    }
}

// ---------------------------------------------------------------------------
// K1: bf16 MFMA GEMM. global_load_lds staging (A fp32, B bf16), FOUR LDS
// buffers, depth-2 prefetch, counted vmcnt (never 0 in steady state) + raw
// s_barrier: loads stay in flight across barriers (T3/T4 minimum).
// Tile: 64 rows x 192 cols, BK=32. 4 waves in 2x2.
// ---------------------------------------------------------------------------
union K1Smem {
    struct { float A[4][64 * 32]; unsigned short B[4][192 * 32]; } s;  // 32+48=80KB
    unsigned short O[64 * 264];  // epilogue staging (33.8 KB)
};

__global__ __launch_bounds__(256) void k1_mfma(
    const float* __restrict__ x, const unsigned short* __restrict__ Bt,
    unsigned short* __restrict__ xw01, float* __restrict__ aggH)
{
    __shared__ K1Smem sm;

    const int tid = threadIdx.x;
    const int row0 = blockIdx.x * 64;
    const int w = tid >> 6;
    const int l = tid & 63;
    const int l16 = l & 15;
    const int koct = l >> 4;
    const int wr = w >> 1;
    const int wc = w & 1;

    f32x4 acc[2][6];
#pragma unroll
    for (int i = 0; i < 2; ++i)
#pragma unroll
        for (int j = 0; j < 6; ++j) acc[i][j] = (f32x4){0.f, 0.f, 0.f, 0.f};

    const int aJg4 = (((l & 7) ^ (l >> 3)) * 4);
    const float* aBase[2];
    int aLdsOff[2];
#pragma unroll
    for (int i = 0; i < 2; ++i) {
        const int rowl = (2 * w + i) * 8 + (l >> 3);
        int grow = row0 + rowl;
        if (grow > N_NODES - 1) grow = N_NODES - 1;
        aBase[i] = x + (size_t)grow * IN_DIM;
        aLdsOff[i] = (2 * w + i) * 256;  // floats
    }
    const int bJg8 = (((l & 3) ^ ((l >> 3) & 3)) * 8);
    const unsigned short* bBase[3];
    int bLdsOff[3];
#pragma unroll
    for (int i = 0; i < 3; ++i) {
        const int coll = (3 * w + i) * 16 + (l >> 2);
        bBase[i] = Bt + (size_t)coll * KP + bJg8;
        bLdsOff[i] = (3 * w + i) * 512;  // ushorts
    }

    const int ja0 = ((2 * koct) ^ (l16 & 7)) * 4;
    const int ja1 = ((2 * koct + 1) ^ (l16 & 7)) * 4;
    const int jb = (koct ^ ((l16 >> 1) & 3)) * 8;

    // issue the 5 staging loads (2 A + 3 B) for step s into buffer s&3
    auto ISSUE = [&](int s) {
        const int k0 = s * 32;
        const int buf = s & 3;
#pragma unroll
        for (int i = 0; i < 2; ++i) {
            int gk = k0 + aJg4; if (gk > IN_DIM - 4) gk = IN_DIM - 4;
            gload16(aBase[i] + gk, &sm.s.A[buf][aLdsOff[i]]);
        }
#pragma unroll
        for (int i = 0; i < 3; ++i)
            gload16(bBase[i] + k0, &sm.s.B[buf][bLdsOff[i]]);
    };

    ISSUE(0);
    ISSUE(1);

#pragma unroll
    for (int s = 0; s < NSTEPS; ++s) {
        if (s + 2 < NSTEPS) ISSUE(s + 2);
        // counted wait: guarantees every wave's step-s loads have landed
        if (s < NSTEPS - 2)       asm volatile("s_waitcnt vmcnt(10)" ::: "memory");
        else if (s == NSTEPS - 2) asm volatile("s_waitcnt vmcnt(5)" ::: "memory");
        else                      asm volatile("s_waitcnt vmcnt(0)" ::: "memory");
        __builtin_amdgcn_s_barrier();
        asm volatile("" ::: "memory");

        const int buf = s & 3;
        const float* LA = sm.s.A[buf];
        const unsigned short* LB = sm.s.B[buf];
        short8 af[2];
#pragma unroll
        for (int rb = 0; rb < 2; ++rb) {
            const int r = wr * 32 + rb * 16 + l16;
            f32x4 f0 = *(const f32x4*)&LA[r * 32 + ja0];
            f32x4 f1 = *(const f32x4*)&LA[r * 32 + ja1];
            short8 a;
            a[0] = (short)f2bf(f0[0]); a[1] = (short)f2bf(f0[1]);
            a[2] = (short)f2bf(f0[2]); a[3] = (short)f2bf(f0[3]);
            a[4] = (short)f2bf(f1[0]); a[5] = (short)f2bf(f1[1]);
            a[6] = (short)f2bf(f1[2]); a[7] = (short)f2bf(f1[3]);
            af[rb] = a;
        }
#pragma unroll
        for (int cf = 0; cf < 6; ++cf) {
            const int c = wc * 96 + cf * 16 + l16;
            short8 bfg = *(const short8*)&LB[c * 32 + jb];
            acc[0][cf] = __builtin_amdgcn_mfma_f32_16x16x32_bf16(af[0], bfg, acc[0][cf], 0, 0, 0);
            acc[1][cf] = __builtin_amdgcn_mfma_f32_16x16x32_bf16(af[1], bfg, acc[1][cf], 0, 0, 0);
        }
    }
    __syncthreads();  // all reads done before O-staging overwrites the union

#pragma unroll
    for (int rb = 0; rb < 2; ++rb)
#pragma unroll
        for (int cf = 0; cf < 6; ++cf) {
            const int cg = wc * 96 + cf * 16 + l16;
            if (96 * wc + cf * 16 < 128) {
#pragma unroll
                for (int reg = 0; reg < 4; ++reg) {
                    const int rloc = wr * 32 + rb * 16 + koct * 4 + reg;
                    const int idx = (cg < 64) ? (2 * cg) : (2 * cg - 127);
                    sm.O[rloc * 264 + idx] = f2bf(acc[rb][cf][reg]);
                }
            } else {
#pragma unroll
                for (int reg = 0; reg < 4; ++reg) {
                    const int r = row0 + wr * 32 + rb * 16 + koct * 4 + reg;
                    if (r < N_NODES) aggH[(size_t)r * HID + (cg - 128)] = acc[rb][cf][reg];
                }
            }
        }
    __syncthreads();
    {
        const int row = tid >> 2, q = tid & 3;
        const int rg = row0 + row;
        if (rg < N_NODES) {
#pragma unroll
            for (int j = 0; j < 4; ++j) {
                uint4 v = *(const uint4*)&sm.O[row * 264 + q * 32 + j * 8];
                *(uint4*)&xw01[(size_t)rg * 128 + q * 32 + j * 8] = v;
            }
        }
    }
}

// ---------------------------------------------------------------------------
// AGG1: wave per node; lane = hidden dim. acc = aggH(root) + sum over edges.
// ---------------------------------------------------------------------------
__global__ __launch_bounds__(256) void agg1(
    const int* __restrict__ off, const uint2* __restrict__ epk,
    const unsigned* __restrict__ xw01_u, float* __restrict__ aggH)
{
    const int n = blockIdx.x * 4 + (threadIdx.x >> 6);
    if (n >= N_NODES) return;
    const int d = threadIdx.x & 63;
    const int start = off[n];
    const int deg = off[n + 1] - start;

    float acc = aggH[(size_t)n * HID + d];
    for (int i = 0; i < deg; i += 4) {
        unsigned srcs[4];
        float w0[4], w1[4];
#pragma unroll
        for (int j = 0; j < 4; ++j) {
            const bool ok = (i + j) < deg;
            const int idx = ok ? (start + i + j) : start;
            const uint2 t = epk[idx];
            const float v = __builtin_bit_cast(float, t.y);
            srcs[j] = t.x;
            w0[j] = ok ? (1.f - v) : 0.f;
            w1[j] = ok ? v : 0.f;
        }
        unsigned g[4];
#pragma unroll
        for (int j = 0; j < 4; ++j) g[j] = xw01_u[(size_t)srcs[j] * 64 + d];
#pragma unroll
        for (int j = 0; j < 4; ++j) {
            acc += w0[j] * bf2f((unsigned short)(g[j] & 0xFFFF));
            acc += w1[j] * bf2f((unsigned short)(g[j] >> 16));
        }
    }
    aggH[(size_t)n * HID + d] = acc;
}

// ---------------------------------------------------------------------------
// K3: h = relu(aggH + b1); hw01 = packed bf16 {h@w2[0], h@w2[1]}; agg2 = h@root2.
// ---------------------------------------------------------------------------
__global__ __launch_bounds__(256) void k3_relu_gemm(
    const float* __restrict__ aggH, const float* __restrict__ b1,
    const float* __restrict__ w2, const float* __restrict__ root2,
    unsigned* __restrict__ hw01_u, float* __restrict__ agg2)
{
    __shared__ float Ws[3 * HID * NCLS];
    __shared__ float Hs[16][HID];

    const int tid = threadIdx.x;
    for (int i = tid; i < 2 * HID * NCLS; i += 256) Ws[i] = w2[i];
    for (int i = tid; i < HID * NCLS; i += 256) Ws[2 * HID * NCLS + i] = root2[i];

    const int n0 = blockIdx.x * 16;
    for (int i = tid; i < 16 * HID; i += 256) {
        const int nl = i >> 6, k = i & 63;
        const float h = aggH[(size_t)(n0 + nl) * HID + k] + b1[k];
        Hs[nl][k] = fmaxf(h, 0.f);
    }
    __syncthreads();

    const int nl = tid >> 4;
    const int c = tid & 15;
    float a0 = 0.f, a1 = 0.f, a2 = 0.f;
#pragma unroll
    for (int k = 0; k < HID; ++k) {
        const float h = Hs[nl][k];
        a0 += h * Ws[0 * HID * NCLS + k * NCLS + c];
        a1 += h * Ws[1 * HID * NCLS + k * NCLS + c];
        a2 += h * Ws[2 * HID * NCLS + k * NCLS + c];
    }
    const size_t o = (size_t)(n0 + nl) * NCLS + c;
    hw01_u[o] = pack2(f2bf(a0), f2bf(a1));
    agg2[o] = a2;
}

// ---------------------------------------------------------------------------
// AGG2 + log_softmax fused: 16 lanes per node, 16 nodes per block.
// ---------------------------------------------------------------------------
__global__ __launch_bounds__(256) void agg2_sm(
    const int* __restrict__ off, const uint2* __restrict__ epk,
    const unsigned* __restrict__ hw01_u, const float* __restrict__ agg2,
    const float* __restrict__ b2, float* __restrict__ out)
{
    const int n = blockIdx.x * 16 + (threadIdx.x >> 4);
    const int c = threadIdx.x & 15;
    const int start = off[n];
    const int deg = off[n + 1] - start;

    float acc = agg2[(size_t)n * NCLS + c];
    for (int i = 0; i < deg; i += 4) {
        unsigned srcs[4];
        float w0[4], w1[4];
#pragma unroll
        for (int j = 0; j < 4; ++j) {
            const bool ok = (i + j) < deg;
            const int idx = ok ? (start + i + j) : start;
            const uint2 t = epk[idx];
            const float v = __builtin_bit_cast(float, t.y);
            srcs[j] = t.x;
            w0[j] = ok ? (1.f - v) : 0.f;
            w1[j] = ok ? v : 0.f;
        }
        unsigned g[4];
#pragma unroll
        for (int j = 0; j < 4; ++j) g[j] = hw01_u[(size_t)srcs[j] * NCLS + c];
#pragma unroll
        for (int j = 0; j < 4; ++j) {
            acc += w0[j] * bf2f((unsigned short)(g[j] & 0xFFFF));
            acc += w1[j] * bf2f((unsigned short)(g[j] >> 16));
        }
    }

    const float z = acc + b2[c];
    float m = z;
#pragma unroll
    for (int s = 1; s < 16; s <<= 1) m = fmaxf(m, __shfl_xor(m, s, 64));
    const float e = expf(z - m);
    float ssum = e;
#pragma unroll
    for (int s = 1; s < 16; s <<= 1) ssum += __shfl_xor(ssum, s, 64);
    out[(size_t)n * NCLS + c] = (z - m) - logf(ssum);
}

extern "C" void kernel_launch(void* const* d_in, const int* in_sizes, int n_in,
                              void* d_out, int out_size, void* d_ws, size_t ws_size,
                              hipStream_t stream) {
    const float* x = (const float*)d_in[0];
    const int* ei = (const int*)d_in[1];
    const float* ea = (const float*)d_in[2];
    const float* w1 = (const float*)d_in[3];
    const float* root1 = (const float*)d_in[4];
    const float* b1 = (const float*)d_in[5];
    const float* w2 = (const float*)d_in[6];
    const float* root2 = (const float*)d_in[7];
    const float* b2 = (const float*)d_in[8];
    float* out = (float*)d_out;

    char* ws = (char*)d_ws;
    unsigned short* xw01 = (unsigned short*)ws;                 // 25.6 MB
    float* aggH = (float*)(ws + 25600000);                      // 25.6 MB
    unsigned* hw01_u = (unsigned*)(ws + 51200000);              // 6.4 MB
    float* agg2 = (float*)(ws + 57600000);                      // 6.4 MB
    unsigned short* Bt = (unsigned short*)(ws + 64000000);      // 0.2 MB
    int* off = (int*)(ws + 64300000);                           // 0.4 MB (NPAD ints)
    int* bkcnt = (int*)(ws + 64750000);                         // 1.6 KB
    int* bkoff = (int*)(ws + 64760000);                         // 1.6 KB
    int* bkcur = (int*)(ws + 64770000);                         // 1.6 KB
    uint2* epk = (uint2*)(ws + 64800000);                       // 12.8 MB
    uint2* epkS = (uint2*)(ws + 77600000);                      // 12.8 MB -> ~90.4 MB

    // CSR build (bucket-level histogram only; per-dst offsets from csr_place)
    csr_bzero<<<1, 512, 0, stream>>>(bkcnt);
    csr_bhist<<<(N_EDGES + EPB - 1) / EPB, 256, 0, stream>>>(ei, bkcnt);
    csr_bscan<<<1, 512, 0, stream>>>(bkcnt, bkoff, bkcur);
    csr_bucket<<<(N_EDGES + EPB - 1) / EPB, 256, 0, stream>>>(ei, ea, bkcur, epk);
    csr_place<<<NBUK, 256, 0, stream>>>(bkoff, epk, epkS, off);

    // layer 1
    k0_bt<<<192, 256, 0, stream>>>(w1, root1, Bt);
    k1_mfma<<<(N_NODES + 63) / 64, 256, 0, stream>>>(x, Bt, xw01, aggH);
    agg1<<<(N_NODES + 3) / 4, 256, 0, stream>>>(off, epkS, (const unsigned*)xw01, aggH);

    // layer 2
    k3_relu_gemm<<<N_NODES / 16, 256, 0, stream>>>(aggH, b1, w2, root2, hw01_u, agg2);
    agg2_sm<<<N_NODES / 16, 256, 0, stream>>>(off, epkS, hw01_u, agg2, b2, out);
}